// Round 8
// baseline (392.402 us; speedup 1.0000x reference)
//
#include <hip/hip_runtime.h>
#include <hip/hip_bf16.h>

#define LOG2E 1.4426950408889634f
#define LN2   0.6931471805599453f
#define NEG2  (-1.4426950e30f)
#define EXP2F(x) __builtin_exp2f(x)
#define LOG2F(x) __builtin_log2f(x)
#define LDEXPF(x,k) __builtin_ldexpf((x),(k))

// DPP wave_shr:1 — whole-wave shift right one lane (lane i gets lane i-1).
__device__ __forceinline__ float dpp_shr1_f(float x, float old) {
    return __int_as_float(__builtin_amdgcn_update_dpp(
        __float_as_int(old), __float_as_int(x), 0x138, 0xF, 0xF, false));
}
__device__ __forceinline__ int dpp_shr1_i(int x, int old) {
    return __builtin_amdgcn_update_dpp(old, x, 0x138, 0xF, 0xF, false);
}

__device__ __forceinline__ unsigned bf16r(float x) {  // round-half-up bf16
    return (__float_as_uint(x) + 0x8000u) >> 16;
}

// async global->LDS (no VGPR data path). size literal per guide.
__device__ __forceinline__ void async16(void* lds, const void* g) {
    __builtin_amdgcn_global_load_lds(
        (const __attribute__((address_space(1))) unsigned int*)g,
        (__attribute__((address_space(3))) unsigned int*)lds, 16, 0, 0);
}
__device__ __forceinline__ void async4(void* lds, const void* g) {
    __builtin_amdgcn_global_load_lds(
        (const __attribute__((address_space(1))) unsigned int*)g,
        (__attribute__((address_space(3))) unsigned int*)lds, 4, 0, 0);
}

// ===========================================================================
// Parallel emission-probability precompute (passing since round 6)
// ===========================================================================
__global__ __launch_bounds__(256) void ph_prob_kernel(
    const float* __restrict__ logits, const int* __restrict__ tgt,
    unsigned short* __restrict__ P) {
    int wid = threadIdx.x >> 6, lane = threadIdx.x & 63;
    int r = blockIdx.x * 4 + wid;               // [0, 64000)
    int b = r / 2000;
    const float* row = logits + (size_t)r * 128;
    __shared__ float ylds[4][128];
    float y0 = row[lane] * LOG2E;
    float y1 = row[lane + 64] * LOG2E;
    ylds[wid][lane] = y0;
    ylds[wid][lane + 64] = y1;
    float m = fmaxf(y0, y1);
#pragma unroll
    for (int i = 1; i < 64; i <<= 1) m = fmaxf(m, __shfl_xor(m, i));
    float s = EXP2F(y0 - m) + EXP2F(y1 - m);
#pragma unroll
    for (int i = 1; i < 64; i <<= 1) s += __shfl_xor(s, i);
    float d2 = m + LOG2F(s);

    int c[4];
#pragma unroll
    for (int k = 0; k < 4; ++k) {
        int i = min(4 * lane + k, 199);
        c[k] = tgt[b * 200 + i];
    }
    float pb = EXP2F(ylds[wid][0] - d2);
    float po[4];
#pragma unroll
    for (int k = 0; k < 4; ++k) po[k] = EXP2F(ylds[wid][c[k]] - d2);

    unsigned h[8];
#pragma unroll
    for (int s2 = 0; s2 < 8; ++s2) {
        int l = 8 * lane + s2;
        float v = (s2 & 1) ? po[s2 >> 1] : pb;
        h[s2] = (l <= 400) ? bf16r(v) : 0u;
    }
    uint4 u;
    u.x = h[0] | (h[1] << 16);
    u.y = h[2] | (h[3] << 16);
    u.z = h[4] | (h[5] << 16);
    u.w = h[6] | (h[7] << 16);
    *(uint4*)(P + (size_t)r * 512 + lane * 8) = u;
}

__global__ __launch_bounds__(256) void err_prob_kernel(
    const float* __restrict__ logits, const int* __restrict__ tgt,
    unsigned short* __restrict__ P) {
    int wid = threadIdx.x >> 6, lane = threadIdx.x & 63;
    int r = blockIdx.x * 4 + wid;
    int b = r / 2000;
    const float* row = logits + (size_t)r * 8;
    __shared__ float ylds[4][8];
    float y = (lane < 8) ? row[lane] * LOG2E : -3.0e38f;
    if (lane < 8) ylds[wid][lane] = y;
    float m = y;
#pragma unroll
    for (int i = 1; i < 64; i <<= 1) m = fmaxf(m, __shfl_xor(m, i));
    float s = EXP2F(y - m);
#pragma unroll
    for (int i = 1; i < 64; i <<= 1) s += __shfl_xor(s, i);
    float d2 = m + LOG2F(s);

    int cc = tgt[b * 50 + min(lane, 49)];
    float pb = EXP2F(ylds[wid][0] - d2);
    float pod = EXP2F(ylds[wid][cc] - d2);
    int l0 = 2 * lane;
    unsigned h0 = (l0 <= 100) ? bf16r(pb) : 0u;
    unsigned h1 = (l0 + 1 <= 100) ? bf16r(pod) : 0u;
    *(unsigned*)(P + (size_t)r * 128 + lane * 2) = h0 | (h1 << 16);
}

// ===========================================================================
// Shared helpers
// ===========================================================================
__device__ __forceinline__ void finish_loss(float capA, float capB, int capEA,
                                            int capEB, int lane,
                                            float* __restrict__ loss_out, int b) {
    float vA = (capA > 0.f) ? (float)capEA + LOG2F(capA) : NEG2;
    float vB = (capB > 0.f) ? (float)capEB + LOG2F(capB) : NEG2;
    float mm = fmaxf(vA, vB);
#pragma unroll
    for (int i = 1; i < 64; i <<= 1) mm = fmaxf(mm, __shfl_xor(mm, i));
    float sum = EXP2F(vA - mm) + EXP2F(vB - mm);
#pragma unroll
    for (int i = 1; i < 64; i <<= 1) sum += __shfl_xor(sum, i);
    if (lane == 0) loss_out[b] = -(mm + LOG2F(sum)) * LN2;
}

// 1-step transition for NST=2 (err), capture + renorm included (round-7 code).
__device__ __forceinline__ void do_step_p2(
    float (&a)[2], int& E, const float (&p)[2], const bool (&skipb)[2],
    int lane, int t, int t_idx, int l1, int l2,
    float& capA, float& capB, int& capEA, int& capEB) {
    if (t == 0) {
#pragma unroll
        for (int s = 0; s < 2; ++s) {
            int l = lane * 2 + s;
            a[s] = (l < 2) ? p[s] : 0.f;
        }
        E = 0;
    } else {
        float top1 = dpp_shr1_f(a[1], 0.f);
        int   En   = dpp_shr1_i(E, E);
        int Ep = max(E, En);
        float t1 = LDEXPF(top1, En - Ep);
        float ao0 = LDEXPF(a[0], E - Ep);
        float ao1 = LDEXPF(a[1], E - Ep);
        E = Ep;
        a[0] = (ao0 + t1) * p[0];
        a[1] = (ao1 + ao0 + (skipb[1] ? t1 : 0.f)) * p[1];
    }
    if (t == t_idx) {
#pragma unroll
        for (int s = 0; s < 2; ++s) {
            int l = lane * 2 + s;
            if (l == l1) { capA = a[s]; capEA = E; }
            if (l == l2) { capB = a[s]; capEB = E; }
        }
    }
    if ((t & 3) == 3) {
        float m = fmaxf(a[0], a[1]);
        int k = ((__float_as_int(m) >> 23) & 255) - 127;
        a[0] = LDEXPF(a[0], -k);
        a[1] = LDEXPF(a[1], -k);
        E += k;
    }
}

// ===========================================================================
// ctc4: single wave per (task,sample); self-prefetch via global_load_lds with
// counted vmcnt (no barriers, no producer). Ph path uses 2-step fused banded-5
// transitions (999 fused iters + 1 plain), err path plain 1-step.
// ===========================================================================
__global__ __launch_bounds__(64) void ctc4_kernel(
    const unsigned short* __restrict__ Perr, const unsigned short* __restrict__ Pph,
    const int* __restrict__ err_tgt, const int* __restrict__ ph_tgt,
    const int* __restrict__ err_il, const int* __restrict__ ph_il,
    const int* __restrict__ err_tl, const int* __restrict__ ph_tl,
    float* __restrict__ loss_err, float* __restrict__ loss_ph, int T) {
    __shared__ unsigned short ring[32 * 512];   // 32 rows x 1024 B = 32 KiB
    const int blk = blockIdx.x;
    const int lane = threadIdx.x & 63;
    const int NCHK = T >> 3;                    // 250

    if (blk < 32) {
        // ---------------- error task: NST=2, row = 256 B ----------------
        const int b = blk;
        const int L = 101;
        int tl = err_tl[b];
        int l1 = min(2 * tl, L - 1);
        int l2 = max(min(2 * tl - 1, L - 1), 0);
        int t_idx = min(max(err_il[b] - 1, 0), T - 1);
        const int* tgt = err_tgt + b * 50;

        bool skipb[2];
        skipb[0] = false;
        {
            int l = lane * 2 + 1;
            bool sk = false;
            if (l >= 3 && l <= 100) { int i = l >> 1; sk = (tgt[i] != tgt[i - 1]); }
            skipb[1] = sk;
        }

        const char* Pb = (const char*)(Perr + (size_t)b * T * 128);
        const char* srcl = Pb + lane * 4;
        char* ringc = (char*)ring;

        asm volatile("s_waitcnt vmcnt(0)" ::: "memory");   // drain setup loads
#pragma unroll
        for (int r = 0; r < 24; ++r)
            async4(ringc + (size_t)(r & 31) * 256, srcl + (size_t)r * 256);
        asm volatile("s_waitcnt vmcnt(8)" ::: "memory");   // chunks 0,1 resident
        __builtin_amdgcn_sched_barrier(0);

        auto rd = [&](int row) -> unsigned {
            return *((const unsigned*)(ringc + (size_t)(row & 31) * 256) + lane);
        };
        unsigned qa = rd(0), qb = rd(1);

        float a[2] = {0.f, 0.f};
        int E = 0;
        float capA = 0.f, capB = 0.f;
        int capEA = 0, capEB = 0;

        for (int k = 0; k < NCHK; ++k) {
            if (k + 3 < NCHK) {
                int base = (k + 3) * 8;
#pragma unroll
                for (int r = 0; r < 8; ++r)
                    async4(ringc + (size_t)((base + r) & 31) * 256,
                           srcl + (size_t)(base + r) * 256);
                asm volatile("s_waitcnt vmcnt(16)" ::: "memory");
            } else {
                asm volatile("s_waitcnt vmcnt(0)" ::: "memory");
            }
            __builtin_amdgcn_sched_barrier(0);
#pragma unroll
            for (int j = 0; j < 8; ++j) {
                int t = (k << 3) + j;
                unsigned cur = qa; qa = qb; qb = rd(t + 2);
                float p[2];
                p[0] = __uint_as_float(cur << 16);
                p[1] = __uint_as_float(cur & 0xFFFF0000u);
                do_step_p2(a, E, p, skipb, lane, t, t_idx, l1, l2,
                           capA, capB, capEA, capEB);
            }
        }
        finish_loss(capA, capB, capEA, capEB, lane, loss_err, b);

    } else {
        // ---------------- phoneme task: NST=8, row = 1024 B, fused 2-step ----
        const int b = blk - 32;
        const int L = 401;
        int tl = ph_tl[b];
        int l1 = min(2 * tl, L - 1);
        int l2 = max(min(2 * tl - 1, L - 1), 0);
        int t_idx = min(max(ph_il[b] - 1, 0), T - 1);
        const int* tgt = ph_tgt + b * 200;

        // static per-state skip machinery
        float skf[8];
#pragma unroll
        for (int s = 0; s < 8; ++s) {
            int l = lane * 8 + s;
            float v = 0.f;
            if ((s & 1) && l >= 3 && l <= 400) {
                int i = l >> 1;
                v = (tgt[i] != tgt[i - 1]) ? 1.f : 0.f;
            }
            skf[s] = v;
        }
        float nsk7 = dpp_shr1_f(skf[7], 0.f);
        float skm1f[8] = {0.f};      // sk_{l-1}, used by even s
        skm1f[0] = nsk7;  skm1f[2] = skf[1];
        skm1f[4] = skf[3]; skm1f[6] = skf[5];
        float skprodf[8] = {0.f};    // sk_l * sk_{l-2}, odd s
        skprodf[1] = skf[1] * nsk7;   skprodf[3] = skf[3] * skf[1];
        skprodf[5] = skf[5] * skf[3]; skprodf[7] = skf[7] * skf[5];

        const char* Pb = (const char*)(Pph + (size_t)b * T * 512);
        const char* srcl = Pb + lane * 16;
        char* ringc = (char*)ring;

        asm volatile("s_waitcnt vmcnt(0)" ::: "memory");
#pragma unroll
        for (int r = 0; r < 24; ++r)
            async16(ringc + (size_t)(r & 31) * 1024, srcl + (size_t)r * 1024);
        asm volatile("s_waitcnt vmcnt(8)" ::: "memory");
        __builtin_amdgcn_sched_barrier(0);

        auto rd4 = [&](int row) -> uint4 {
            return *((const uint4*)(ringc + (size_t)(row & 31) * 1024) + lane);
        };
        auto unpack = [&](const uint4& q, float (&p)[8]) {
            p[0] = __uint_as_float(q.x << 16);
            p[1] = __uint_as_float(q.x & 0xFFFF0000u);
            p[2] = __uint_as_float(q.y << 16);
            p[3] = __uint_as_float(q.y & 0xFFFF0000u);
            p[4] = __uint_as_float(q.z << 16);
            p[5] = __uint_as_float(q.z & 0xFFFF0000u);
            p[6] = __uint_as_float(q.w << 16);
            p[7] = __uint_as_float(q.w & 0xFFFF0000u);
        };

        float a[8];
#pragma unroll
        for (int s = 0; s < 8; ++s) a[s] = 0.f;
        int E = 0;
        float capA = 0.f, capB = 0.f;
        int capEA = 0, capEB = 0;

        auto cap = [&](const float (&v)[8], int Ev) {
#pragma unroll
            for (int s = 0; s < 8; ++s) {
                int l = lane * 8 + s;
                if (l == l1) { capA = v[s]; capEA = Ev; }
                if (l == l2) { capB = v[s]; capEB = Ev; }
            }
        };
        // plain 1-step values (no commit): v = (a + a[-1] + sk*a[-2]) * pp
        auto plain_vals = [&](const float (&ain)[8], int Ein, const float (&pp)[8],
                              float (&v)[8], int& Eout) {
            float n7 = dpp_shr1_f(ain[7], 0.f);
            float n6 = dpp_shr1_f(ain[6], 0.f);
            int En = dpp_shr1_i(Ein, Ein);
            int Ep = max(Ein, En);
            float o[8];
#pragma unroll
            for (int s = 0; s < 8; ++s) o[s] = LDEXPF(ain[s], Ein - Ep);
            float s7 = LDEXPF(n7, En - Ep), s6 = LDEXPF(n6, En - Ep);
#pragma unroll
            for (int s = 0; s < 8; ++s) {
                float am1 = (s == 0) ? s7 : o[s - 1];
                float am2 = (s == 0) ? s6 : (s == 1) ? s7 : o[s - 2];
                v[s] = __builtin_fmaf(skf[s], am2, o[s] + am1) * pp[s];
            }
            Eout = Ep;
        };

        // t = 0 init from row 0
        {
            uint4 q0 = rd4(0);
            float p0[8];
            unpack(q0, p0);
#pragma unroll
            for (int s = 0; s < 8; ++s) {
                int l = lane * 8 + s;
                a[s] = (l < 2) ? p0[s] : 0.f;
            }
            if (t_idx == 0) cap(a, 0);
        }
        uint4 q1 = rd4(1), q2 = rd4(2);

        // fused iteration body: applies rows ta=2i+1, tb=2i+2
        auto fused_iter = [&](int i) {
            int ta = 2 * i + 1;
            float p1v[8], p2v[8];
            unpack(q1, p1v);
            unpack(q2, p2v);
            q1 = rd4(ta + 2);
            q2 = rd4(ta + 3);

            if (ta == t_idx) {           // capture at intermediate step (rare)
                float v[8]; int Ev;
                plain_vals(a, E, p1v, v, Ev);
                cap(v, Ev);
            }

            // neighbor values
            float n7 = dpp_shr1_f(a[7], 0.f);
            float n6 = dpp_shr1_f(a[6], 0.f);
            float n5 = dpp_shr1_f(a[5], 0.f);
            float n4 = dpp_shr1_f(a[4], 0.f);
            float np7 = dpp_shr1_f(p1v[7], 0.f);
            float np6 = dpp_shr1_f(p1v[6], 0.f);
            int En = dpp_shr1_i(E, E);
            int Ep = max(E, En);
            float o[8];
#pragma unroll
            for (int s = 0; s < 8; ++s) o[s] = LDEXPF(a[s], E - Ep);
            float s7 = LDEXPF(n7, En - Ep), s6 = LDEXPF(n6, En - Ep);
            float s5 = LDEXPF(n5, En - Ep), s4 = LDEXPF(n4, En - Ep);
            E = Ep;

            float an[8];
#pragma unroll
            for (int s = 0; s < 8; ++s) {
                float am1 = (s == 0) ? s7 : o[s - 1];
                float am2 = (s == 0) ? s6 : (s == 1) ? s7 : o[s - 2];
                float am3 = (s == 0) ? s5 : (s == 1) ? s6 : (s == 2) ? s7 : o[s - 3];
                float am4 = (s == 0) ? s4 : (s == 1) ? s5 : (s == 2) ? s6
                              : (s == 3) ? s7 : o[s - 4];
                float p1m1 = (s == 0) ? np7 : p1v[s - 1];
                float p1m2 = (s == 0) ? np6 : (s == 1) ? np7 : p1v[s - 2];
                float c1 = p1v[s] + p1m1;
                float sum;
                if ((s & 1) == 0) {
                    float c3 = skm1f[s] * p1m1;
                    sum = p1v[s] * o[s];
                    sum = __builtin_fmaf(c1, am1, sum);
                    sum = __builtin_fmaf(p1m1, am2, sum);
                    sum = __builtin_fmaf(c3, am3, sum);
                } else {
                    float tq = p1v[s] + p1m2;
                    float c2 = __builtin_fmaf(skf[s], tq, p1m1);
                    float c3 = skf[s] * p1m2;
                    float c4 = skprodf[s] * p1m2;
                    sum = p1v[s] * o[s];
                    sum = __builtin_fmaf(c1, am1, sum);
                    sum = __builtin_fmaf(c2, am2, sum);
                    sum = __builtin_fmaf(c3, am3, sum);
                    sum = __builtin_fmaf(c4, am4, sum);
                }
                an[s] = sum * p2v[s];
            }
#pragma unroll
            for (int s = 0; s < 8; ++s) a[s] = an[s];

            if (ta + 1 == t_idx) cap(a, E);

            if ((i & 1) == 1) {   // renorm every 2 fused iters (4 t-steps)
                float m = a[0];
#pragma unroll
                for (int s = 1; s < 8; ++s) m = fmaxf(m, a[s]);
                int kk = ((__float_as_int(m) >> 23) & 255) - 127;
#pragma unroll
                for (int s = 0; s < 8; ++s) a[s] = LDEXPF(a[s], -kk);
                E += kk;
            }
        };

        // main loop: groups of 4 fused iters (8 rows / chunk)
        for (int g = 0; g < 249; ++g) {
            if (g + 3 < NCHK) {
                int base = (g + 3) * 8;
#pragma unroll
                for (int r = 0; r < 8; ++r)
                    async16(ringc + (size_t)((base + r) & 31) * 1024,
                            srcl + (size_t)(base + r) * 1024);
                asm volatile("s_waitcnt vmcnt(16)" ::: "memory");
            } else {
                asm volatile("s_waitcnt vmcnt(0)" ::: "memory");
            }
            __builtin_amdgcn_sched_barrier(0);
#pragma unroll
            for (int ii = 0; ii < 4; ++ii) fused_iter(g * 4 + ii);
        }
        asm volatile("s_waitcnt vmcnt(0)" ::: "memory");
        __builtin_amdgcn_sched_barrier(0);
        fused_iter(996); fused_iter(997); fused_iter(998);   // rows 1993..1998
        // final plain step t = 1999 (row in q1)
        {
            float pF[8];
            unpack(q1, pF);
            float v[8]; int Ev;
            plain_vals(a, E, pF, v, Ev);
#pragma unroll
            for (int s = 0; s < 8; ++s) a[s] = v[s];
            E = Ev;
            if (t_idx == T - 1) cap(a, E);
        }
        finish_loss(capA, capB, capEA, capEB, lane, loss_ph, b);
    }
}

// ===========================================================================
// FALLBACK PATH (round-5, passing) — used only if ws_size too small
// ===========================================================================
__global__ void denom_err_kernel(const float* __restrict__ logits,
                                 float* __restrict__ d2, int rows) {
    int r = blockIdx.x * blockDim.x + threadIdx.x;
    if (r >= rows) return;
    const float* row = logits + (size_t)r * 8;
    float x[8];
#pragma unroll
    for (int i = 0; i < 8; ++i) x[i] = row[i] * LOG2E;
    float m = x[0];
#pragma unroll
    for (int i = 1; i < 8; ++i) m = fmaxf(m, x[i]);
    float s = 0.f;
#pragma unroll
    for (int i = 0; i < 8; ++i) s += EXP2F(x[i] - m);
    d2[r] = m + LOG2F(s);
}

__global__ void denom_ph_kernel(const float* __restrict__ logits,
                                float* __restrict__ d2, int rows) {
    int wave = (int)((blockIdx.x * (size_t)blockDim.x + threadIdx.x) >> 6);
    int lane = threadIdx.x & 63;
    if (wave >= rows) return;
    const float* row = logits + (size_t)wave * 128;
    float x0 = row[lane] * LOG2E;
    float x1 = row[lane + 64] * LOG2E;
    float m = fmaxf(x0, x1);
#pragma unroll
    for (int i = 1; i < 64; i <<= 1) m = fmaxf(m, __shfl_xor(m, i));
    float s = EXP2F(x0 - m) + EXP2F(x1 - m);
#pragma unroll
    for (int i = 1; i < 64; i <<= 1) s += __shfl_xor(s, i);
    if (lane == 0) d2[wave] = m + LOG2F(s);
}

template <int NST, int C>
__device__ __forceinline__ void gather_row(const float* ringL, const float* ringD,
                                           int row, const int (&clsoff)[NST],
                                           float (&g)[NST], float& gd) {
    int base = (row & 63) * C;
#pragma unroll
    for (int s = 0; s < NST; ++s) g[s] = ringL[base + clsoff[s]];
    gd = ringD[row & 63];
}

template <int C, int CHV>
__device__ __forceinline__ void stage_load(const float* __restrict__ lrow,
                                           const float* __restrict__ d2row,
                                           int t0, int T, int lane,
                                           float4 (&st)[CHV], float4& stD) {
#pragma unroll
    for (int j = 0; j < CHV; ++j) {
        int e = t0 * C + (j * 64 + lane) * 4;
        e = min(e, T * C - 4);
        st[j] = *(const float4*)(lrow + e);
    }
    if (lane < 8) {
        int e = t0 + lane * 4;
        e = min(e, T - 4);
        stD = *(const float4*)(d2row + e);
    }
}

template <int C, int CHV>
__device__ __forceinline__ void stage_write(float* ringL, float* ringD, int t0, int lane,
                                            const float4 (&st)[CHV], const float4& stD) {
    int base = (t0 & 63) * C;
#pragma unroll
    for (int j = 0; j < CHV; ++j)
        *(float4*)(ringL + base + (j * 64 + lane) * 4) = st[j];
    if (lane < 8)
        *(float4*)(ringD + (t0 & 63) + lane * 4) = stD;
}

template <int NST>
__device__ __forceinline__ void do_step_lin(
    float (&a)[NST], int& E,
    const float (&g)[NST], float gd,
    const float (&validf)[NST], const bool (&skipb)[NST],
    int lane, int t, int t_idx, int l1, int l2,
    float& capA, float& capB, int& capEA, int& capEB) {
    float p[NST];
#pragma unroll
    for (int s = 0; s < NST; ++s)
        p[s] = validf[s] * EXP2F(__builtin_fmaf(g[s], LOG2E, -gd));
    if (t == 0) {
#pragma unroll
        for (int s = 0; s < NST; ++s) {
            int l = lane * NST + s;
            a[s] = (l < 2) ? p[s] : 0.f;
        }
        E = 0;
    } else {
        float top1 = dpp_shr1_f(a[NST - 1], 0.f);
        int   En   = dpp_shr1_i(E, E);
        int Ep = max(E, En);
        float t1 = LDEXPF(top1, En - Ep);
        float ao[NST];
#pragma unroll
        for (int s = 0; s < NST; ++s) ao[s] = LDEXPF(a[s], E - Ep);
        E = Ep;
#pragma unroll
        for (int s = 0; s < NST; ++s) {
            float sum;
            if (s == 0)            sum = ao[0] + t1;
            else if (s == 1)       sum = ao[1] + ao[0] + (skipb[1] ? t1 : 0.f);
            else if ((s & 1) == 0) sum = ao[s] + ao[s - 1];
            else                   sum = ao[s] + ao[s - 1] + (skipb[s] ? ao[s - 2] : 0.f);
            a[s] = sum * p[s];
        }
    }
    if (t == t_idx) {
#pragma unroll
        for (int s = 0; s < NST; ++s) {
            int l = lane * NST + s;
            if (l == l1) { capA = a[s]; capEA = E; }
            if (l == l2) { capB = a[s]; capEB = E; }
        }
    }
    if ((t & 1) == 1) {
        float m = a[0];
#pragma unroll
        for (int s = 1; s < NST; ++s) m = fmaxf(m, a[s]);
        int k = ((__float_as_int(m) >> 23) & 255) - 127;
#pragma unroll
        for (int s = 0; s < NST; ++s) a[s] = LDEXPF(a[s], -k);
        E += k;
    }
}

template <int NST, int C, int S, int CHV>
__device__ __forceinline__ void ctc_run(
    const float* __restrict__ lrow, const float* __restrict__ d2row,
    const int* __restrict__ tgt, int T, int t_idx, int l1, int l2,
    float* ringL, float* ringD, float* __restrict__ loss_out, int b) {
    const int lane = threadIdx.x & 63;
    const int L = 2 * S + 1;
    int clsoff[NST];
    bool skipb[NST];
    float validf[NST];
#pragma unroll
    for (int s = 0; s < NST; ++s) {
        int l = lane * NST + s;
        bool v = (l < L);
        int li = v ? l : 0;
        int c = 0;
        bool sk = false;
        if (li & 1) {
            int i = li >> 1;
            c = tgt[i];
            if (li >= 3) sk = (c != tgt[i - 1]);
        }
        clsoff[s] = c;
        skipb[s] = sk;
        validf[s] = v ? 1.f : 0.f;
    }
    float4 st[CHV];
    float4 stD = make_float4(0.f, 0.f, 0.f, 0.f);
    stage_load<C, CHV>(lrow, d2row, 0, T, lane, st, stD);
    stage_write<C, CHV>(ringL, ringD, 0, lane, st, stD);
    stage_load<C, CHV>(lrow, d2row, 32, T, lane, st, stD);
    stage_write<C, CHV>(ringL, ringD, 32, lane, st, stD);
    stage_load<C, CHV>(lrow, d2row, 64, T, lane, st, stD);
    float gA[NST], gB[NST], dA, dB;
    gather_row<NST, C>(ringL, ringD, 0, clsoff, gA, dA);
    gather_row<NST, C>(ringL, ringD, 1, clsoff, gB, dB);
    float a[NST];
#pragma unroll
    for (int s = 0; s < NST; ++s) a[s] = 0.f;
    int E = 0;
    float capA = 0.f, capB = 0.f;
    int capEA = 0, capEB = 0;
    const int NCH = (T + 31) >> 5;
    for (int c = 0; c < NCH; ++c) {
        int t0 = c << 5;
        int half = min(32, T - t0) >> 1;
        for (int j = 0; j < half; ++j) {
            int t = t0 + 2 * j;
            do_step_lin<NST>(a, E, gA, dA, validf, skipb, lane, t, t_idx, l1, l2,
                             capA, capB, capEA, capEB);
            gather_row<NST, C>(ringL, ringD, t + 2, clsoff, gA, dA);
            do_step_lin<NST>(a, E, gB, dB, validf, skipb, lane, t + 1, t_idx, l1, l2,
                             capA, capB, capEA, capEB);
            gather_row<NST, C>(ringL, ringD, t + 3, clsoff, gB, dB);
            if (j == 14 && c + 2 < NCH) {
                stage_write<C, CHV>(ringL, ringD, t0 + 64, lane, st, stD);
                if (c + 3 < NCH)
                    stage_load<C, CHV>(lrow, d2row, t0 + 96, T, lane, st, stD);
            }
        }
    }
    float vA = (capA > 0.f) ? (float)capEA + LOG2F(capA) : NEG2;
    float vB = (capB > 0.f) ? (float)capEB + LOG2F(capB) : NEG2;
    float mm = fmaxf(vA, vB);
#pragma unroll
    for (int i = 1; i < 64; i <<= 1) mm = fmaxf(mm, __shfl_xor(mm, i));
    float sum = EXP2F(vA - mm) + EXP2F(vB - mm);
#pragma unroll
    for (int i = 1; i < 64; i <<= 1) sum += __shfl_xor(sum, i);
    if (lane == 0) loss_out[b] = -(mm + LOG2F(sum)) * LN2;
}

__global__ __launch_bounds__(64) void ctc_kernel(
    const float* __restrict__ err_logits, const float* __restrict__ ph_logits,
    const int* __restrict__ err_tgt, const int* __restrict__ ph_tgt,
    const int* __restrict__ err_il, const int* __restrict__ ph_il,
    const int* __restrict__ err_tl, const int* __restrict__ ph_tl,
    const float* __restrict__ d2_err, const float* __restrict__ d2_ph,
    float* __restrict__ loss_err, float* __restrict__ loss_ph, int T) {
    __shared__ float ringL[64 * 128];
    __shared__ float ringD[64];
    int blk = blockIdx.x;
    if (blk < 32) {
        int b = blk;
        const int L = 101;
        int tl = err_tl[b];
        int l1 = min(2 * tl, L - 1);
        int l2 = max(min(2 * tl - 1, L - 1), 0);
        int t_idx = min(max(err_il[b] - 1, 0), T - 1);
        ctc_run<2, 8, 50, 1>(err_logits + (size_t)b * T * 8, d2_err + (size_t)b * T,
                             err_tgt + b * 50, T, t_idx, l1, l2, ringL, ringD,
                             loss_err, b);
    } else {
        int b = blk - 32;
        const int L = 401;
        int tl = ph_tl[b];
        int l1 = min(2 * tl, L - 1);
        int l2 = max(min(2 * tl - 1, L - 1), 0);
        int t_idx = min(max(ph_il[b] - 1, 0), T - 1);
        ctc_run<8, 128, 200, 16>(ph_logits + (size_t)b * T * 128, d2_ph + (size_t)b * T,
                                 ph_tgt + b * 200, T, t_idx, l1, l2, ringL, ringD,
                                 loss_ph, b);
    }
}

// ---------------------------------------------------------------------------
// Final: focal transform + means + total. One wave.
// ---------------------------------------------------------------------------
__global__ void final_kernel(const float* __restrict__ loss_err,
                             const float* __restrict__ loss_ph,
                             float* __restrict__ out) {
    int lane = threadIdx.x & 63;
    float fe = 0.f, fp = 0.f;
    if (lane < 32) {
        float l = fmaxf(loss_err[lane], 1e-6f);
        float pt = fminf(fmaxf(EXP2F(-l * LOG2E), 1e-6f), 1.0f);
        float om = 1.f - pt;
        fe = om * om * l;
        l = fmaxf(loss_ph[lane], 1e-6f);
        pt = fminf(fmaxf(EXP2F(-l * LOG2E), 1e-6f), 1.0f);
        om = 1.f - pt;
        fp = om * om * l;
    }
#pragma unroll
    for (int i = 1; i < 64; i <<= 1) {
        fe += __shfl_xor(fe, i);
        fp += __shfl_xor(fp, i);
    }
    if (lane == 0) {
        float err = fe / 32.f;
        float ph = fp / 32.f;
        out[0] = err + ph;
        out[1] = err;
        out[2] = ph;
    }
}

// ---------------------------------------------------------------------------
extern "C" void kernel_launch(void* const* d_in, const int* in_sizes, int n_in,
                              void* d_out, int out_size, void* d_ws, size_t ws_size,
                              hipStream_t stream) {
    const int B = 32, T = 2000;
    const float* err_logits = (const float*)d_in[0];  // [32,2000,8]
    const float* ph_logits  = (const float*)d_in[1];  // [32,2000,128]
    const int* err_tgt = (const int*)d_in[2];         // [32,50]
    const int* ph_tgt  = (const int*)d_in[3];         // [32,200]
    const int* err_il  = (const int*)d_in[4];
    const int* ph_il   = (const int*)d_in[5];
    const int* err_tl  = (const int*)d_in[6];
    const int* ph_tl   = (const int*)d_in[7];
    float* out = (float*)d_out;

    const size_t PH_US  = (size_t)B * T * 512;   // ushorts
    const size_t ERR_US = (size_t)B * T * 128;   // ushorts
    const size_t need = (PH_US + ERR_US) * 2 + 256;

    if (ws_size >= need) {
        // -------- fast path --------
        unsigned short* Pph  = (unsigned short*)d_ws;
        unsigned short* Perr = Pph + PH_US;
        float* loss_err = (float*)(Perr + ERR_US);
        float* loss_ph  = loss_err + 32;

        ph_prob_kernel<<<(B * T) / 4, 256, 0, stream>>>(ph_logits, ph_tgt, Pph);
        err_prob_kernel<<<(B * T) / 4, 256, 0, stream>>>(err_logits, err_tgt, Perr);
        ctc4_kernel<<<64, 64, 0, stream>>>(Perr, Pph, err_tgt, ph_tgt,
                                           err_il, ph_il, err_tl, ph_tl,
                                           loss_err, loss_ph, T);
        final_kernel<<<1, 64, 0, stream>>>(loss_err, loss_ph, out);
    } else {
        // -------- fallback (round-5) --------
        float* ws = (float*)d_ws;
        float* d2_err   = ws;
        float* d2_ph    = ws + 64000;
        float* loss_err = ws + 128000;
        float* loss_ph  = ws + 128032;
        int rows = B * T;
        denom_err_kernel<<<(rows + 255) / 256, 256, 0, stream>>>(err_logits, d2_err, rows);
        denom_ph_kernel<<<rows / 4, 256, 0, stream>>>(ph_logits, d2_ph, rows);
        ctc_kernel<<<64, 64, 0, stream>>>(err_logits, ph_logits, err_tgt, ph_tgt,
                                          err_il, ph_il, err_tl, ph_tl,
                                          d2_err, d2_ph, loss_err, loss_ph, T);
        final_kernel<<<1, 64, 0, stream>>>(loss_err, loss_ph, out);
    }
}

// Round 9
// 391.052 us; speedup vs baseline: 1.0035x; 1.0035x over previous
//
#include <hip/hip_runtime.h>
#include <hip/hip_bf16.h>

#define LOG2E 1.4426950408889634f
#define LN2   0.6931471805599453f
#define NEG2  (-1.4426950e30f)
#define EXP2F(x) __builtin_exp2f(x)
#define LOG2F(x) __builtin_log2f(x)
#define LDEXPF(x,k) __builtin_ldexpf((x),(k))

// DPP wave_shr:1 — whole-wave shift right one lane (lane i gets lane i-1).
__device__ __forceinline__ float dpp_shr1_f(float x, float old) {
    return __int_as_float(__builtin_amdgcn_update_dpp(
        __float_as_int(old), __float_as_int(x), 0x138, 0xF, 0xF, false));
}
__device__ __forceinline__ int dpp_shr1_i(int x, int old) {
    return __builtin_amdgcn_update_dpp(old, x, 0x138, 0xF, 0xF, false);
}

__device__ __forceinline__ unsigned bf16r(float x) {  // round-half-up bf16
    return (__float_as_uint(x) + 0x8000u) >> 16;
}

// async global->LDS (no VGPR data path). size literal per guide.
__device__ __forceinline__ void async16(void* lds, const void* g) {
    __builtin_amdgcn_global_load_lds(
        (const __attribute__((address_space(1))) unsigned int*)g,
        (__attribute__((address_space(3))) unsigned int*)lds, 16, 0, 0);
}
__device__ __forceinline__ void async4(void* lds, const void* g) {
    __builtin_amdgcn_global_load_lds(
        (const __attribute__((address_space(1))) unsigned int*)g,
        (__attribute__((address_space(3))) unsigned int*)lds, 4, 0, 0);
}

// ===========================================================================
// Parallel emission-probability precompute (passing since round 6)
// ===========================================================================
__global__ __launch_bounds__(256) void ph_prob_kernel(
    const float* __restrict__ logits, const int* __restrict__ tgt,
    unsigned short* __restrict__ P) {
    int wid = threadIdx.x >> 6, lane = threadIdx.x & 63;
    int r = blockIdx.x * 4 + wid;               // [0, 64000)
    int b = r / 2000;
    const float* row = logits + (size_t)r * 128;
    __shared__ float ylds[4][128];
    float y0 = row[lane] * LOG2E;
    float y1 = row[lane + 64] * LOG2E;
    ylds[wid][lane] = y0;
    ylds[wid][lane + 64] = y1;
    float m = fmaxf(y0, y1);
#pragma unroll
    for (int i = 1; i < 64; i <<= 1) m = fmaxf(m, __shfl_xor(m, i));
    float s = EXP2F(y0 - m) + EXP2F(y1 - m);
#pragma unroll
    for (int i = 1; i < 64; i <<= 1) s += __shfl_xor(s, i);
    float d2 = m + LOG2F(s);

    int c[4];
#pragma unroll
    for (int k = 0; k < 4; ++k) {
        int i = min(4 * lane + k, 199);
        c[k] = tgt[b * 200 + i];
    }
    float pb = EXP2F(ylds[wid][0] - d2);
    float po[4];
#pragma unroll
    for (int k = 0; k < 4; ++k) po[k] = EXP2F(ylds[wid][c[k]] - d2);

    unsigned h[8];
#pragma unroll
    for (int s2 = 0; s2 < 8; ++s2) {
        int l = 8 * lane + s2;
        float v = (s2 & 1) ? po[s2 >> 1] : pb;
        h[s2] = (l <= 400) ? bf16r(v) : 0u;
    }
    uint4 u;
    u.x = h[0] | (h[1] << 16);
    u.y = h[2] | (h[3] << 16);
    u.z = h[4] | (h[5] << 16);
    u.w = h[6] | (h[7] << 16);
    *(uint4*)(P + (size_t)r * 512 + lane * 8) = u;
}

__global__ __launch_bounds__(256) void err_prob_kernel(
    const float* __restrict__ logits, const int* __restrict__ tgt,
    unsigned short* __restrict__ P) {
    int wid = threadIdx.x >> 6, lane = threadIdx.x & 63;
    int r = blockIdx.x * 4 + wid;
    int b = r / 2000;
    const float* row = logits + (size_t)r * 8;
    __shared__ float ylds[4][8];
    float y = (lane < 8) ? row[lane] * LOG2E : -3.0e38f;
    if (lane < 8) ylds[wid][lane] = y;
    float m = y;
#pragma unroll
    for (int i = 1; i < 64; i <<= 1) m = fmaxf(m, __shfl_xor(m, i));
    float s = EXP2F(y - m);
#pragma unroll
    for (int i = 1; i < 64; i <<= 1) s += __shfl_xor(s, i);
    float d2 = m + LOG2F(s);

    int cc = tgt[b * 50 + min(lane, 49)];
    float pb = EXP2F(ylds[wid][0] - d2);
    float pod = EXP2F(ylds[wid][cc] - d2);
    int l0 = 2 * lane;
    unsigned h0 = (l0 <= 100) ? bf16r(pb) : 0u;
    unsigned h1 = (l0 + 1 <= 100) ? bf16r(pod) : 0u;
    *(unsigned*)(P + (size_t)r * 128 + lane * 2) = h0 | (h1 << 16);
}

// ===========================================================================
// Shared helpers
// ===========================================================================
__device__ __forceinline__ void finish_loss(float capA, float capB, int capEA,
                                            int capEB, int lane,
                                            float* __restrict__ loss_out, int b) {
    float vA = (capA > 0.f) ? (float)capEA + LOG2F(capA) : NEG2;
    float vB = (capB > 0.f) ? (float)capEB + LOG2F(capB) : NEG2;
    float mm = fmaxf(vA, vB);
#pragma unroll
    for (int i = 1; i < 64; i <<= 1) mm = fmaxf(mm, __shfl_xor(mm, i));
    float sum = EXP2F(vA - mm) + EXP2F(vB - mm);
#pragma unroll
    for (int i = 1; i < 64; i <<= 1) sum += __shfl_xor(sum, i);
    if (lane == 0) loss_out[b] = -(mm + LOG2F(sum)) * LN2;
}

// ===========================================================================
// ctc5: single wave per (task,sample); self-prefetch via global_load_lds ring
// (counted vmcnt, no barriers). LDS->reg reads BATCHED one chunk (8 rows) at
// a time into a double-buffered q[8]: one counted lgkm wait per 8 steps
// instead of a full LDS-latency wait per step. Plain 1-step transitions.
// ===========================================================================
__global__ __launch_bounds__(64) void ctc5_kernel(
    const unsigned short* __restrict__ Perr, const unsigned short* __restrict__ Pph,
    const int* __restrict__ err_tgt, const int* __restrict__ ph_tgt,
    const int* __restrict__ err_il, const int* __restrict__ ph_il,
    const int* __restrict__ err_tl, const int* __restrict__ ph_tl,
    float* __restrict__ loss_err, float* __restrict__ loss_ph, int T) {
    __shared__ unsigned short ring[32 * 512];   // 32 rows x 1024 B = 32 KiB
    const int blk = blockIdx.x;
    const int lane = threadIdx.x & 63;
    const int NCHK = T >> 3;                    // 250 (even)

    if (blk < 32) {
        // ---------------- error task: NST=2, row = 256 B ----------------
        const int b = blk;
        const int L = 101;
        int tl = err_tl[b];
        int l1 = min(2 * tl, L - 1);
        int l2 = max(min(2 * tl - 1, L - 1), 0);
        int t_idx = min(max(err_il[b] - 1, 0), T - 1);
        const int* tgt = err_tgt + b * 50;

        bool skip1;
        {
            int l = lane * 2 + 1;
            bool sk = false;
            if (l >= 3 && l <= 100) { int i = l >> 1; sk = (tgt[i] != tgt[i - 1]); }
            skip1 = sk;
        }

        const char* srcl = (const char*)(Perr + (size_t)b * T * 128) + lane * 4;
        char* ringc = (char*)ring;

        asm volatile("s_waitcnt vmcnt(0)" ::: "memory");   // drain setup loads
#pragma unroll
        for (int r = 0; r < 24; ++r)
            async4(ringc + (size_t)(r & 31) * 256, srcl + (size_t)r * 256);
        asm volatile("s_waitcnt vmcnt(8)" ::: "memory");   // chunks 0,1 resident
        __builtin_amdgcn_sched_barrier(0);

        auto rd = [&](int row) -> unsigned {
            return *((const unsigned*)(ringc + (size_t)(row & 31) * 256) + lane);
        };

        float a[2] = {0.f, 0.f};
        int E = 0;
        float capA = 0.f, capB = 0.f;
        int capEA = 0, capEB = 0;

        auto step2 = [&](unsigned cur, int t) {
            float p0 = __uint_as_float(cur << 16);
            float p1 = __uint_as_float(cur & 0xFFFF0000u);
            if (t == 0) {
                a[0] = (lane == 0) ? p0 : 0.f;
                a[1] = (lane == 0) ? p1 : 0.f;
                E = 0;
            } else {
                float top1 = dpp_shr1_f(a[1], 0.f);
                int   En   = dpp_shr1_i(E, E);
                int Ep = max(E, En);
                float t1 = LDEXPF(top1, En - Ep);
                float ao0 = LDEXPF(a[0], E - Ep);
                float ao1 = LDEXPF(a[1], E - Ep);
                E = Ep;
                a[0] = (ao0 + t1) * p0;
                a[1] = (ao1 + ao0 + (skip1 ? t1 : 0.f)) * p1;
            }
            if (t == t_idx) {
#pragma unroll
                for (int s = 0; s < 2; ++s) {
                    int l = lane * 2 + s;
                    if (l == l1) { capA = a[s]; capEA = E; }
                    if (l == l2) { capB = a[s]; capEB = E; }
                }
            }
            if ((t & 3) == 3) {
                float m = fmaxf(a[0], a[1]);
                int k = ((__float_as_int(m) >> 23) & 255) - 127;
                a[0] = LDEXPF(a[0], -k);
                a[1] = LDEXPF(a[1], -k);
                E += k;
            }
        };

        unsigned qA[8], qB[8];
#pragma unroll
        for (int j = 0; j < 8; ++j) qA[j] = rd(j);   // chunk 0

        auto chunk_body = [&](int k, unsigned (&qc)[8], unsigned (&qn)[8]) {
            if (k + 3 < NCHK) {
                int base = (k + 3) * 8;
#pragma unroll
                for (int r = 0; r < 8; ++r)
                    async4(ringc + (size_t)((base + r) & 31) * 256,
                           srcl + (size_t)(base + r) * 256);
                asm volatile("s_waitcnt vmcnt(16)" ::: "memory");
            } else {
                asm volatile("s_waitcnt vmcnt(0)" ::: "memory");
            }
            __builtin_amdgcn_sched_barrier(0);
            if (k + 1 < NCHK) {
                int base = (k + 1) * 8;
#pragma unroll
                for (int j = 0; j < 8; ++j) qn[j] = rd(base + j);
            }
#pragma unroll
            for (int j = 0; j < 8; ++j) step2(qc[j], (k << 3) + j);
        };

        for (int k = 0; k < NCHK; k += 2) {
            chunk_body(k, qA, qB);
            chunk_body(k + 1, qB, qA);
        }
        finish_loss(capA, capB, capEA, capEB, lane, loss_err, b);

    } else {
        // ---------------- phoneme task: NST=8, row = 1024 B ----------------
        const int b = blk - 32;
        const int L = 401;
        int tl = ph_tl[b];
        int l1 = min(2 * tl, L - 1);
        int l2 = max(min(2 * tl - 1, L - 1), 0);
        int t_idx = min(max(ph_il[b] - 1, 0), T - 1);
        const int* tgt = ph_tgt + b * 200;

        float skf[8];
#pragma unroll
        for (int s = 0; s < 8; ++s) {
            int l = lane * 8 + s;
            float v = 0.f;
            if ((s & 1) && l >= 3 && l <= 400) {
                int i = l >> 1;
                v = (tgt[i] != tgt[i - 1]) ? 1.f : 0.f;
            }
            skf[s] = v;
        }

        const char* srcl = (const char*)(Pph + (size_t)b * T * 512) + lane * 16;
        char* ringc = (char*)ring;

        asm volatile("s_waitcnt vmcnt(0)" ::: "memory");
#pragma unroll
        for (int r = 0; r < 24; ++r)
            async16(ringc + (size_t)(r & 31) * 1024, srcl + (size_t)r * 1024);
        asm volatile("s_waitcnt vmcnt(8)" ::: "memory");
        __builtin_amdgcn_sched_barrier(0);

        auto rd4 = [&](int row) -> uint4 {
            return *((const uint4*)(ringc + (size_t)(row & 31) * 1024) + lane);
        };

        float a[8];
#pragma unroll
        for (int s = 0; s < 8; ++s) a[s] = 0.f;
        int E = 0;
        float capA = 0.f, capB = 0.f;
        int capEA = 0, capEB = 0;

        auto step8 = [&](const uint4& q, int t) {
            float p[8];
            p[0] = __uint_as_float(q.x << 16);
            p[1] = __uint_as_float(q.x & 0xFFFF0000u);
            p[2] = __uint_as_float(q.y << 16);
            p[3] = __uint_as_float(q.y & 0xFFFF0000u);
            p[4] = __uint_as_float(q.z << 16);
            p[5] = __uint_as_float(q.z & 0xFFFF0000u);
            p[6] = __uint_as_float(q.w << 16);
            p[7] = __uint_as_float(q.w & 0xFFFF0000u);
            if (t == 0) {
#pragma unroll
                for (int s = 0; s < 8; ++s) {
                    int l = lane * 8 + s;
                    a[s] = (l < 2) ? p[s] : 0.f;
                }
                E = 0;
            } else {
                float n7 = dpp_shr1_f(a[7], 0.f);
                float n6 = dpp_shr1_f(a[6], 0.f);
                int   En = dpp_shr1_i(E, E);
                int Ep = max(E, En);
                float o[8];
#pragma unroll
                for (int s = 0; s < 8; ++s) o[s] = LDEXPF(a[s], E - Ep);
                float s7 = LDEXPF(n7, En - Ep);
                float s6 = LDEXPF(n6, En - Ep);
                E = Ep;
#pragma unroll
                for (int s = 0; s < 8; ++s) {
                    float am1 = (s == 0) ? s7 : o[s - 1];
                    float am2 = (s == 0) ? s6 : (s == 1) ? s7 : o[s - 2];
                    a[s] = __builtin_fmaf(skf[s], am2, o[s] + am1) * p[s];
                }
            }
            if (t == t_idx) {
#pragma unroll
                for (int s = 0; s < 8; ++s) {
                    int l = lane * 8 + s;
                    if (l == l1) { capA = a[s]; capEA = E; }
                    if (l == l2) { capB = a[s]; capEB = E; }
                }
            }
            if ((t & 3) == 3) {
                float m = a[0];
#pragma unroll
                for (int s = 1; s < 8; ++s) m = fmaxf(m, a[s]);
                int kk = ((__float_as_int(m) >> 23) & 255) - 127;
#pragma unroll
                for (int s = 0; s < 8; ++s) a[s] = LDEXPF(a[s], -kk);
                E += kk;
            }
        };

        uint4 qA[8], qB[8];
#pragma unroll
        for (int j = 0; j < 8; ++j) qA[j] = rd4(j);   // chunk 0

        auto chunk_body = [&](int k, uint4 (&qc)[8], uint4 (&qn)[8]) {
            if (k + 3 < NCHK) {
                int base = (k + 3) * 8;
#pragma unroll
                for (int r = 0; r < 8; ++r)
                    async16(ringc + (size_t)((base + r) & 31) * 1024,
                            srcl + (size_t)(base + r) * 1024);
                asm volatile("s_waitcnt vmcnt(16)" ::: "memory");
            } else {
                asm volatile("s_waitcnt vmcnt(0)" ::: "memory");
            }
            __builtin_amdgcn_sched_barrier(0);
            if (k + 1 < NCHK) {
                int base = (k + 1) * 8;
#pragma unroll
                for (int j = 0; j < 8; ++j) qn[j] = rd4(base + j);
            }
#pragma unroll
            for (int j = 0; j < 8; ++j) step8(qc[j], (k << 3) + j);
        };

        for (int k = 0; k < NCHK; k += 2) {
            chunk_body(k, qA, qB);
            chunk_body(k + 1, qB, qA);
        }
        finish_loss(capA, capB, capEA, capEB, lane, loss_ph, b);
    }
}

// ===========================================================================
// FALLBACK PATH (round-5, passing) — used only if ws_size too small
// ===========================================================================
__global__ void denom_err_kernel(const float* __restrict__ logits,
                                 float* __restrict__ d2, int rows) {
    int r = blockIdx.x * blockDim.x + threadIdx.x;
    if (r >= rows) return;
    const float* row = logits + (size_t)r * 8;
    float x[8];
#pragma unroll
    for (int i = 0; i < 8; ++i) x[i] = row[i] * LOG2E;
    float m = x[0];
#pragma unroll
    for (int i = 1; i < 8; ++i) m = fmaxf(m, x[i]);
    float s = 0.f;
#pragma unroll
    for (int i = 0; i < 8; ++i) s += EXP2F(x[i] - m);
    d2[r] = m + LOG2F(s);
}

__global__ void denom_ph_kernel(const float* __restrict__ logits,
                                float* __restrict__ d2, int rows) {
    int wave = (int)((blockIdx.x * (size_t)blockDim.x + threadIdx.x) >> 6);
    int lane = threadIdx.x & 63;
    if (wave >= rows) return;
    const float* row = logits + (size_t)wave * 128;
    float x0 = row[lane] * LOG2E;
    float x1 = row[lane + 64] * LOG2E;
    float m = fmaxf(x0, x1);
#pragma unroll
    for (int i = 1; i < 64; i <<= 1) m = fmaxf(m, __shfl_xor(m, i));
    float s = EXP2F(x0 - m) + EXP2F(x1 - m);
#pragma unroll
    for (int i = 1; i < 64; i <<= 1) s += __shfl_xor(s, i);
    if (lane == 0) d2[wave] = m + LOG2F(s);
}

template <int NST, int C>
__device__ __forceinline__ void gather_row(const float* ringL, const float* ringD,
                                           int row, const int (&clsoff)[NST],
                                           float (&g)[NST], float& gd) {
    int base = (row & 63) * C;
#pragma unroll
    for (int s = 0; s < NST; ++s) g[s] = ringL[base + clsoff[s]];
    gd = ringD[row & 63];
}

template <int C, int CHV>
__device__ __forceinline__ void stage_load(const float* __restrict__ lrow,
                                           const float* __restrict__ d2row,
                                           int t0, int T, int lane,
                                           float4 (&st)[CHV], float4& stD) {
#pragma unroll
    for (int j = 0; j < CHV; ++j) {
        int e = t0 * C + (j * 64 + lane) * 4;
        e = min(e, T * C - 4);
        st[j] = *(const float4*)(lrow + e);
    }
    if (lane < 8) {
        int e = t0 + lane * 4;
        e = min(e, T - 4);
        stD = *(const float4*)(d2row + e);
    }
}

template <int C, int CHV>
__device__ __forceinline__ void stage_write(float* ringL, float* ringD, int t0, int lane,
                                            const float4 (&st)[CHV], const float4& stD) {
    int base = (t0 & 63) * C;
#pragma unroll
    for (int j = 0; j < CHV; ++j)
        *(float4*)(ringL + base + (j * 64 + lane) * 4) = st[j];
    if (lane < 8)
        *(float4*)(ringD + (t0 & 63) + lane * 4) = stD;
}

template <int NST>
__device__ __forceinline__ void do_step_lin(
    float (&a)[NST], int& E,
    const float (&g)[NST], float gd,
    const float (&validf)[NST], const bool (&skipb)[NST],
    int lane, int t, int t_idx, int l1, int l2,
    float& capA, float& capB, int& capEA, int& capEB) {
    float p[NST];
#pragma unroll
    for (int s = 0; s < NST; ++s)
        p[s] = validf[s] * EXP2F(__builtin_fmaf(g[s], LOG2E, -gd));
    if (t == 0) {
#pragma unroll
        for (int s = 0; s < NST; ++s) {
            int l = lane * NST + s;
            a[s] = (l < 2) ? p[s] : 0.f;
        }
        E = 0;
    } else {
        float top1 = dpp_shr1_f(a[NST - 1], 0.f);
        int   En   = dpp_shr1_i(E, E);
        int Ep = max(E, En);
        float t1 = LDEXPF(top1, En - Ep);
        float ao[NST];
#pragma unroll
        for (int s = 0; s < NST; ++s) ao[s] = LDEXPF(a[s], E - Ep);
        E = Ep;
#pragma unroll
        for (int s = 0; s < NST; ++s) {
            float sum;
            if (s == 0)            sum = ao[0] + t1;
            else if (s == 1)       sum = ao[1] + ao[0] + (skipb[1] ? t1 : 0.f);
            else if ((s & 1) == 0) sum = ao[s] + ao[s - 1];
            else                   sum = ao[s] + ao[s - 1] + (skipb[s] ? ao[s - 2] : 0.f);
            a[s] = sum * p[s];
        }
    }
    if (t == t_idx) {
#pragma unroll
        for (int s = 0; s < NST; ++s) {
            int l = lane * NST + s;
            if (l == l1) { capA = a[s]; capEA = E; }
            if (l == l2) { capB = a[s]; capEB = E; }
        }
    }
    if ((t & 1) == 1) {
        float m = a[0];
#pragma unroll
        for (int s = 1; s < NST; ++s) m = fmaxf(m, a[s]);
        int k = ((__float_as_int(m) >> 23) & 255) - 127;
#pragma unroll
        for (int s = 0; s < NST; ++s) a[s] = LDEXPF(a[s], -k);
        E += k;
    }
}

template <int NST, int C, int S, int CHV>
__device__ __forceinline__ void ctc_run(
    const float* __restrict__ lrow, const float* __restrict__ d2row,
    const int* __restrict__ tgt, int T, int t_idx, int l1, int l2,
    float* ringL, float* ringD, float* __restrict__ loss_out, int b) {
    const int lane = threadIdx.x & 63;
    const int L = 2 * S + 1;
    int clsoff[NST];
    bool skipb[NST];
    float validf[NST];
#pragma unroll
    for (int s = 0; s < NST; ++s) {
        int l = lane * NST + s;
        bool v = (l < L);
        int li = v ? l : 0;
        int c = 0;
        bool sk = false;
        if (li & 1) {
            int i = li >> 1;
            c = tgt[i];
            if (li >= 3) sk = (c != tgt[i - 1]);
        }
        clsoff[s] = c;
        skipb[s] = sk;
        validf[s] = v ? 1.f : 0.f;
    }
    float4 st[CHV];
    float4 stD = make_float4(0.f, 0.f, 0.f, 0.f);
    stage_load<C, CHV>(lrow, d2row, 0, T, lane, st, stD);
    stage_write<C, CHV>(ringL, ringD, 0, lane, st, stD);
    stage_load<C, CHV>(lrow, d2row, 32, T, lane, st, stD);
    stage_write<C, CHV>(ringL, ringD, 32, lane, st, stD);
    stage_load<C, CHV>(lrow, d2row, 64, T, lane, st, stD);
    float gA[NST], gB[NST], dA, dB;
    gather_row<NST, C>(ringL, ringD, 0, clsoff, gA, dA);
    gather_row<NST, C>(ringL, ringD, 1, clsoff, gB, dB);
    float a[NST];
#pragma unroll
    for (int s = 0; s < NST; ++s) a[s] = 0.f;
    int E = 0;
    float capA = 0.f, capB = 0.f;
    int capEA = 0, capEB = 0;
    const int NCH = (T + 31) >> 5;
    for (int c = 0; c < NCH; ++c) {
        int t0 = c << 5;
        int half = min(32, T - t0) >> 1;
        for (int j = 0; j < half; ++j) {
            int t = t0 + 2 * j;
            do_step_lin<NST>(a, E, gA, dA, validf, skipb, lane, t, t_idx, l1, l2,
                             capA, capB, capEA, capEB);
            gather_row<NST, C>(ringL, ringD, t + 2, clsoff, gA, dA);
            do_step_lin<NST>(a, E, gB, dB, validf, skipb, lane, t + 1, t_idx, l1, l2,
                             capA, capB, capEA, capEB);
            gather_row<NST, C>(ringL, ringD, t + 3, clsoff, gB, dB);
            if (j == 14 && c + 2 < NCH) {
                stage_write<C, CHV>(ringL, ringD, t0 + 64, lane, st, stD);
                if (c + 3 < NCH)
                    stage_load<C, CHV>(lrow, d2row, t0 + 96, T, lane, st, stD);
            }
        }
    }
    float vA = (capA > 0.f) ? (float)capEA + LOG2F(capA) : NEG2;
    float vB = (capB > 0.f) ? (float)capEB + LOG2F(capB) : NEG2;
    float mm = fmaxf(vA, vB);
#pragma unroll
    for (int i = 1; i < 64; i <<= 1) mm = fmaxf(mm, __shfl_xor(mm, i));
    float sum = EXP2F(vA - mm) + EXP2F(vB - mm);
#pragma unroll
    for (int i = 1; i < 64; i <<= 1) sum += __shfl_xor(sum, i);
    if (lane == 0) loss_out[b] = -(mm + LOG2F(sum)) * LN2;
}

__global__ __launch_bounds__(64) void ctc_kernel(
    const float* __restrict__ err_logits, const float* __restrict__ ph_logits,
    const int* __restrict__ err_tgt, const int* __restrict__ ph_tgt,
    const int* __restrict__ err_il, const int* __restrict__ ph_il,
    const int* __restrict__ err_tl, const int* __restrict__ ph_tl,
    const float* __restrict__ d2_err, const float* __restrict__ d2_ph,
    float* __restrict__ loss_err, float* __restrict__ loss_ph, int T) {
    __shared__ float ringL[64 * 128];
    __shared__ float ringD[64];
    int blk = blockIdx.x;
    if (blk < 32) {
        int b = blk;
        const int L = 101;
        int tl = err_tl[b];
        int l1 = min(2 * tl, L - 1);
        int l2 = max(min(2 * tl - 1, L - 1), 0);
        int t_idx = min(max(err_il[b] - 1, 0), T - 1);
        ctc_run<2, 8, 50, 1>(err_logits + (size_t)b * T * 8, d2_err + (size_t)b * T,
                             err_tgt + b * 50, T, t_idx, l1, l2, ringL, ringD,
                             loss_err, b);
    } else {
        int b = blk - 32;
        const int L = 401;
        int tl = ph_tl[b];
        int l1 = min(2 * tl, L - 1);
        int l2 = max(min(2 * tl - 1, L - 1), 0);
        int t_idx = min(max(ph_il[b] - 1, 0), T - 1);
        ctc_run<8, 128, 200, 16>(ph_logits + (size_t)b * T * 128, d2_ph + (size_t)b * T,
                                 ph_tgt + b * 200, T, t_idx, l1, l2, ringL, ringD,
                                 loss_ph, b);
    }
}

// ---------------------------------------------------------------------------
// Final: focal transform + means + total. One wave.
// ---------------------------------------------------------------------------
__global__ void final_kernel(const float* __restrict__ loss_err,
                             const float* __restrict__ loss_ph,
                             float* __restrict__ out) {
    int lane = threadIdx.x & 63;
    float fe = 0.f, fp = 0.f;
    if (lane < 32) {
        float l = fmaxf(loss_err[lane], 1e-6f);
        float pt = fminf(fmaxf(EXP2F(-l * LOG2E), 1e-6f), 1.0f);
        float om = 1.f - pt;
        fe = om * om * l;
        l = fmaxf(loss_ph[lane], 1e-6f);
        pt = fminf(fmaxf(EXP2F(-l * LOG2E), 1e-6f), 1.0f);
        om = 1.f - pt;
        fp = om * om * l;
    }
#pragma unroll
    for (int i = 1; i < 64; i <<= 1) {
        fe += __shfl_xor(fe, i);
        fp += __shfl_xor(fp, i);
    }
    if (lane == 0) {
        float err = fe / 32.f;
        float ph = fp / 32.f;
        out[0] = err + ph;
        out[1] = err;
        out[2] = ph;
    }
}

// ---------------------------------------------------------------------------
extern "C" void kernel_launch(void* const* d_in, const int* in_sizes, int n_in,
                              void* d_out, int out_size, void* d_ws, size_t ws_size,
                              hipStream_t stream) {
    const int B = 32, T = 2000;
    const float* err_logits = (const float*)d_in[0];  // [32,2000,8]
    const float* ph_logits  = (const float*)d_in[1];  // [32,2000,128]
    const int* err_tgt = (const int*)d_in[2];         // [32,50]
    const int* ph_tgt  = (const int*)d_in[3];         // [32,200]
    const int* err_il  = (const int*)d_in[4];
    const int* ph_il   = (const int*)d_in[5];
    const int* err_tl  = (const int*)d_in[6];
    const int* ph_tl   = (const int*)d_in[7];
    float* out = (float*)d_out;

    const size_t PH_US  = (size_t)B * T * 512;   // ushorts
    const size_t ERR_US = (size_t)B * T * 128;   // ushorts
    const size_t need = (PH_US + ERR_US) * 2 + 256;

    if (ws_size >= need) {
        // -------- fast path --------
        unsigned short* Pph  = (unsigned short*)d_ws;
        unsigned short* Perr = Pph + PH_US;
        float* loss_err = (float*)(Perr + ERR_US);
        float* loss_ph  = loss_err + 32;

        ph_prob_kernel<<<(B * T) / 4, 256, 0, stream>>>(ph_logits, ph_tgt, Pph);
        err_prob_kernel<<<(B * T) / 4, 256, 0, stream>>>(err_logits, err_tgt, Perr);
        ctc5_kernel<<<64, 64, 0, stream>>>(Perr, Pph, err_tgt, ph_tgt,
                                           err_il, ph_il, err_tl, ph_tl,
                                           loss_err, loss_ph, T);
        final_kernel<<<1, 64, 0, stream>>>(loss_err, loss_ph, out);
    } else {
        // -------- fallback (round-5) --------
        float* ws = (float*)d_ws;
        float* d2_err   = ws;
        float* d2_ph    = ws + 64000;
        float* loss_err = ws + 128000;
        float* loss_ph  = ws + 128032;
        int rows = B * T;
        denom_err_kernel<<<(rows + 255) / 256, 256, 0, stream>>>(err_logits, d2_err, rows);
        denom_ph_kernel<<<rows / 4, 256, 0, stream>>>(ph_logits, d2_ph, rows);
        ctc_kernel<<<64, 64, 0, stream>>>(err_logits, ph_logits, err_tgt, ph_tgt,
                                          err_il, ph_il, err_tl, ph_tl,
                                          d2_err, d2_ph, loss_err, loss_ph, T);
        final_kernel<<<1, 64, 0, stream>>>(loss_err, loss_ph, out);
    }
}

// Round 10
// 184.436 us; speedup vs baseline: 2.1276x; 2.1203x over previous
//
#include <hip/hip_runtime.h>
#include <hip/hip_bf16.h>

#define LOG2E 1.4426950408889634f
#define LN2   0.6931471805599453f
#define NEG2  (-1.4426950e30f)
#define EXP2F(x) __builtin_exp2f(x)
#define LOG2F(x) __builtin_log2f(x)
#define LDEXPF(x,k) __builtin_ldexpf((x),(k))

// DPP whole-wave shifts. shr: lane i <- lane i-1 (lane0 gets old).
//                        shl: lane i <- lane i+1 (lane63 gets old).
__device__ __forceinline__ float dpp_shr1_f(float x, float old) {
    return __int_as_float(__builtin_amdgcn_update_dpp(
        __float_as_int(old), __float_as_int(x), 0x138, 0xF, 0xF, false));
}
__device__ __forceinline__ int dpp_shr1_i(int x, int old) {
    return __builtin_amdgcn_update_dpp(old, x, 0x138, 0xF, 0xF, false);
}
__device__ __forceinline__ float dpp_shl1_f(float x, float old) {
    return __int_as_float(__builtin_amdgcn_update_dpp(
        __float_as_int(old), __float_as_int(x), 0x130, 0xF, 0xF, false));
}
__device__ __forceinline__ int dpp_shl1_i(int x, int old) {
    return __builtin_amdgcn_update_dpp(old, x, 0x130, 0xF, 0xF, false);
}

__device__ __forceinline__ unsigned bf16r(float x) {
    return (__float_as_uint(x) + 0x8000u) >> 16;
}

__device__ __forceinline__ void async16(void* lds, const void* g) {
    __builtin_amdgcn_global_load_lds(
        (const __attribute__((address_space(1))) unsigned int*)g,
        (__attribute__((address_space(3))) unsigned int*)lds, 16, 0, 0);
}
__device__ __forceinline__ void async4(void* lds, const void* g) {
    __builtin_amdgcn_global_load_lds(
        (const __attribute__((address_space(1))) unsigned int*)g,
        (__attribute__((address_space(3))) unsigned int*)lds, 4, 0, 0);
}

__device__ __forceinline__ void unpack8(const uint4& q, float (&p)[8]) {
    p[0] = __uint_as_float(q.x << 16);
    p[1] = __uint_as_float(q.x & 0xFFFF0000u);
    p[2] = __uint_as_float(q.y << 16);
    p[3] = __uint_as_float(q.y & 0xFFFF0000u);
    p[4] = __uint_as_float(q.z << 16);
    p[5] = __uint_as_float(q.z & 0xFFFF0000u);
    p[6] = __uint_as_float(q.w << 16);
    p[7] = __uint_as_float(q.w & 0xFFFF0000u);
}

// ===========================================================================
// Parallel emission-probability precompute (passing since round 6)
// ===========================================================================
__global__ __launch_bounds__(256) void ph_prob_kernel(
    const float* __restrict__ logits, const int* __restrict__ tgt,
    unsigned short* __restrict__ P) {
    int wid = threadIdx.x >> 6, lane = threadIdx.x & 63;
    int r = blockIdx.x * 4 + wid;
    int b = r / 2000;
    const float* row = logits + (size_t)r * 128;
    __shared__ float ylds[4][128];
    float y0 = row[lane] * LOG2E;
    float y1 = row[lane + 64] * LOG2E;
    ylds[wid][lane] = y0;
    ylds[wid][lane + 64] = y1;
    float m = fmaxf(y0, y1);
#pragma unroll
    for (int i = 1; i < 64; i <<= 1) m = fmaxf(m, __shfl_xor(m, i));
    float s = EXP2F(y0 - m) + EXP2F(y1 - m);
#pragma unroll
    for (int i = 1; i < 64; i <<= 1) s += __shfl_xor(s, i);
    float d2 = m + LOG2F(s);

    int c[4];
#pragma unroll
    for (int k = 0; k < 4; ++k) {
        int i = min(4 * lane + k, 199);
        c[k] = tgt[b * 200 + i];
    }
    float pb = EXP2F(ylds[wid][0] - d2);
    float po[4];
#pragma unroll
    for (int k = 0; k < 4; ++k) po[k] = EXP2F(ylds[wid][c[k]] - d2);

    unsigned h[8];
#pragma unroll
    for (int s2 = 0; s2 < 8; ++s2) {
        int l = 8 * lane + s2;
        float v = (s2 & 1) ? po[s2 >> 1] : pb;
        h[s2] = (l <= 400) ? bf16r(v) : 0u;
    }
    uint4 u;
    u.x = h[0] | (h[1] << 16);
    u.y = h[2] | (h[3] << 16);
    u.z = h[4] | (h[5] << 16);
    u.w = h[6] | (h[7] << 16);
    *(uint4*)(P + (size_t)r * 512 + lane * 8) = u;
}

__global__ __launch_bounds__(256) void err_prob_kernel(
    const float* __restrict__ logits, const int* __restrict__ tgt,
    unsigned short* __restrict__ P) {
    int wid = threadIdx.x >> 6, lane = threadIdx.x & 63;
    int r = blockIdx.x * 4 + wid;
    int b = r / 2000;
    const float* row = logits + (size_t)r * 8;
    __shared__ float ylds[4][8];
    float y = (lane < 8) ? row[lane] * LOG2E : -3.0e38f;
    if (lane < 8) ylds[wid][lane] = y;
    float m = y;
#pragma unroll
    for (int i = 1; i < 64; i <<= 1) m = fmaxf(m, __shfl_xor(m, i));
    float s = EXP2F(y - m);
#pragma unroll
    for (int i = 1; i < 64; i <<= 1) s += __shfl_xor(s, i);
    float d2 = m + LOG2F(s);

    int cc = tgt[b * 50 + min(lane, 49)];
    float pb = EXP2F(ylds[wid][0] - d2);
    float pod = EXP2F(ylds[wid][cc] - d2);
    int l0 = 2 * lane;
    unsigned h0 = (l0 <= 100) ? bf16r(pb) : 0u;
    unsigned h1 = (l0 + 1 <= 100) ? bf16r(pod) : 0u;
    *(unsigned*)(P + (size_t)r * 128 + lane * 2) = h0 | (h1 << 16);
}

// ===========================================================================
// Shared helpers
// ===========================================================================
__device__ __forceinline__ void finish_loss(float capA, float capB, int capEA,
                                            int capEB, int lane,
                                            float* __restrict__ loss_out, int b) {
    float vA = (capA > 0.f) ? (float)capEA + LOG2F(capA) : NEG2;
    float vB = (capB > 0.f) ? (float)capEB + LOG2F(capB) : NEG2;
    float mm = fmaxf(vA, vB);
#pragma unroll
    for (int i = 1; i < 64; i <<= 1) mm = fmaxf(mm, __shfl_xor(mm, i));
    float sum = EXP2F(vA - mm) + EXP2F(vB - mm);
#pragma unroll
    for (int i = 1; i < 64; i <<= 1) sum += __shfl_xor(sum, i);
    if (lane == 0) loss_out[b] = -(mm + LOG2F(sum)) * LN2;
}

// ===========================================================================
// ctc6: fwd/bwd split. 128 blocks x 64 threads:
//  0..31  err forward  (alpha 0..T/2-1, dump state)  [or full-fwd fallback]
// 32..63  err backward (g T-1..T/2, dump state)
// 64..95  ph  forward
// 96..127 ph  backward
// Fast path requires t_idx == T-1 (true for given inputs); otherwise the fwd
// block runs the full forward with capture and writes the loss directly.
// ===========================================================================
__global__ __launch_bounds__(64) void ctc6_kernel(
    const unsigned short* __restrict__ Perr, const unsigned short* __restrict__ Pph,
    const int* __restrict__ err_tgt, const int* __restrict__ ph_tgt,
    const int* __restrict__ err_il, const int* __restrict__ ph_il,
    const int* __restrict__ err_tl, const int* __restrict__ ph_tl,
    float* __restrict__ aerr, int* __restrict__ aerrE,
    float* __restrict__ gerr, int* __restrict__ gerrE,
    float* __restrict__ aph, int* __restrict__ aphE,
    float* __restrict__ gph, int* __restrict__ gphE,
    float* __restrict__ loss_err, float* __restrict__ loss_ph, int T) {
    __shared__ unsigned short ring[32 * 512];
    char* ringc = (char*)ring;
    const int blk = blockIdx.x;
    const int lane = threadIdx.x & 63;
    const int NR = T >> 1;          // rows per direction (1000)
    const int NCH = NR >> 3;        // chunks (125)

    if (blk < 32) {
        // ---------------- err forward ----------------
        const int b = blk;
        int t_idx = min(max(err_il[b] - 1, 0), T - 1);
        const int* tgt = err_tgt + b * 50;
        float skip1f;
        {
            int l = lane * 2 + 1; bool sk = false;
            if (l >= 3 && l <= 100) { int i = l >> 1; sk = (tgt[i] != tgt[i - 1]); }
            skip1f = sk ? 1.f : 0.f;
        }
        const char* base = (const char*)(Perr + (size_t)b * T * 128);
        float a0 = 0.f, a1 = 0.f; int E = 0;

        auto fstep = [&](unsigned cur, bool rn) {
            float p0 = __uint_as_float(cur << 16);
            float p1 = __uint_as_float(cur & 0xFFFF0000u);
            float n1 = dpp_shr1_f(a1, 0.f);
            int En = dpp_shr1_i(E, E);
            int Ep = max(E, En);
            float t1 = LDEXPF(n1, En - Ep);
            float o0 = LDEXPF(a0, E - Ep), o1 = LDEXPF(a1, E - Ep);
            E = Ep;
            a0 = (o0 + t1) * p0;
            a1 = __builtin_fmaf(skip1f, t1, o1 + o0) * p1;
            if (rn) {
                float m = fmaxf(a0, a1);
                int k = ((__float_as_int(m) >> 23) & 255) - 127;
                a0 = LDEXPF(a0, -k); a1 = LDEXPF(a1, -k); E += k;
            }
        };

        if (t_idx == T - 1) {
            const char* srcl = base + lane * 4;
            auto rd = [&](int row) -> unsigned {
                return *((const unsigned*)(ringc + (size_t)(row & 31) * 256) + lane);
            };
#pragma unroll
            for (int r = 0; r < 24; ++r)
                async4(ringc + (size_t)(r & 31) * 256, srcl + (size_t)r * 256);
            {   // chunk 0 (peeled init)
#pragma unroll
                for (int r = 24; r < 32; ++r)
                    async4(ringc + (size_t)(r & 31) * 256, srcl + (size_t)r * 256);
                asm volatile("s_waitcnt vmcnt(16)" ::: "memory");
                __builtin_amdgcn_sched_barrier(0);
                unsigned q[8];
#pragma unroll
                for (int j = 0; j < 8; ++j) q[j] = rd(j);
                float p0 = __uint_as_float(q[0] << 16);
                float p1 = __uint_as_float(q[0] & 0xFFFF0000u);
                a0 = (lane == 0) ? p0 : 0.f;
                a1 = (lane == 0) ? p1 : 0.f;
                E = 0;
#pragma unroll
                for (int j = 1; j < 8; ++j) fstep(q[j], (j == 3) || (j == 7));
            }
            for (int k = 1; k < NCH; ++k) {
                if (k + 3 < NCH) {
                    int bs = (k + 3) * 8;
#pragma unroll
                    for (int r = 0; r < 8; ++r)
                        async4(ringc + (size_t)((bs + r) & 31) * 256,
                               srcl + (size_t)(bs + r) * 256);
                    asm volatile("s_waitcnt vmcnt(16)" ::: "memory");
                } else {
                    asm volatile("s_waitcnt vmcnt(0)" ::: "memory");
                }
                __builtin_amdgcn_sched_barrier(0);
                unsigned q[8];
#pragma unroll
                for (int j = 0; j < 8; ++j) q[j] = rd(k * 8 + j);
#pragma unroll
                for (int j = 0; j < 8; ++j) fstep(q[j], (j == 3) || (j == 7));
            }
            aerr[b * 128 + lane * 2] = a0;
            aerr[b * 128 + lane * 2 + 1] = a1;
            aerrE[b * 64 + lane] = E;
        } else {
            // fallback: full forward with capture, direct loads (rare path)
            const int L = 101; int tl = err_tl[b];
            int l1 = min(2 * tl, L - 1), l2 = max(min(2 * tl - 1, L - 1), 0);
            float capA = 0.f, capB = 0.f; int capEA = 0, capEB = 0;
            for (int t = 0; t < T; ++t) {
                unsigned cur = *((const unsigned*)(base + (size_t)t * 256) + lane);
                if (t == 0) {
                    float p0 = __uint_as_float(cur << 16);
                    float p1 = __uint_as_float(cur & 0xFFFF0000u);
                    a0 = (lane == 0) ? p0 : 0.f;
                    a1 = (lane == 0) ? p1 : 0.f;
                    E = 0;
                } else {
                    fstep(cur, false);
                }
                if (t == t_idx) {
                    int l0 = lane * 2;
                    if (l0 == l1) { capA = a0; capEA = E; }
                    if (l0 == l2) { capB = a0; capEB = E; }
                    if (l0 + 1 == l1) { capA = a1; capEA = E; }
                    if (l0 + 1 == l2) { capB = a1; capEB = E; }
                }
                if ((t & 3) == 3) {
                    float m = fmaxf(a0, a1);
                    int k = ((__float_as_int(m) >> 23) & 255) - 127;
                    a0 = LDEXPF(a0, -k); a1 = LDEXPF(a1, -k); E += k;
                }
            }
            finish_loss(capA, capB, capEA, capEB, lane, loss_err, b);
        }

    } else if (blk < 64) {
        // ---------------- err backward ----------------
        const int b = blk - 32;
        const int* tgt = err_tgt + b * 50;
        const int L = 101; int tl = err_tl[b];
        int l1 = min(2 * tl, L - 1), l2 = max(min(2 * tl - 1, L - 1), 0);
        float skip1f;
        {
            int l = lane * 2 + 1; bool sk = false;
            if (l >= 3 && l <= 100) { int i = l >> 1; sk = (tgt[i] != tgt[i - 1]); }
            skip1f = sk ? 1.f : 0.f;
        }
        float skp2 = dpp_shl1_f(skip1f, 0.f);  // allow_skip at l+2 for odd l
        const char* base = (const char*)(Perr + (size_t)b * T * 128);
        const char* srcl = base + (size_t)(T - 1) * 256 + lane * 4;  // row u: -u*256
        auto rd = [&](int row) -> unsigned {
            return *((const unsigned*)(ringc + (size_t)(row & 31) * 256) + lane);
        };
        float g0 = 0.f, g1 = 0.f; int E = 0;
        auto bstep = [&](unsigned cur, bool rn) {
            float p0 = __uint_as_float(cur << 16);
            float p1 = __uint_as_float(cur & 0xFFFF0000u);
            float nb0 = dpp_shl1_f(g0, 0.f), nb1 = dpp_shl1_f(g1, 0.f);
            int En = dpp_shl1_i(E, E);
            int Ep = max(E, En);
            float o0 = LDEXPF(g0, E - Ep), o1 = LDEXPF(g1, E - Ep);
            float t0 = LDEXPF(nb0, En - Ep), t1 = LDEXPF(nb1, En - Ep);
            E = Ep;
            g0 = (o0 + o1) * p0;
            g1 = __builtin_fmaf(skp2, t1, o1 + t0) * p1;
            if (rn) {
                float m = fmaxf(g0, g1);
                int k = ((__float_as_int(m) >> 23) & 255) - 127;
                g0 = LDEXPF(g0, -k); g1 = LDEXPF(g1, -k); E += k;
            }
        };
#pragma unroll
        for (int r = 0; r < 24; ++r)
            async4(ringc + (size_t)(r & 31) * 256, srcl - (size_t)r * 256);
        {   // chunk 0: init at t=T-1
#pragma unroll
            for (int r = 24; r < 32; ++r)
                async4(ringc + (size_t)(r & 31) * 256, srcl - (size_t)r * 256);
            asm volatile("s_waitcnt vmcnt(16)" ::: "memory");
            __builtin_amdgcn_sched_barrier(0);
            unsigned q[8];
#pragma unroll
            for (int j = 0; j < 8; ++j) q[j] = rd(j);
            float p0 = __uint_as_float(q[0] << 16);
            float p1 = __uint_as_float(q[0] & 0xFFFF0000u);
            int l0 = lane * 2;
            g0 = (l0 == l1 || l0 == l2) ? p0 : 0.f;
            g1 = (l0 + 1 == l1 || l0 + 1 == l2) ? p1 : 0.f;
            E = 0;
#pragma unroll
            for (int j = 1; j < 8; ++j) bstep(q[j], (j == 3) || (j == 7));
        }
        for (int k = 1; k < NCH; ++k) {
            if (k + 3 < NCH) {
                int bs = (k + 3) * 8;
#pragma unroll
                for (int r = 0; r < 8; ++r)
                    async4(ringc + (size_t)((bs + r) & 31) * 256,
                           srcl - (size_t)(bs + r) * 256);
                asm volatile("s_waitcnt vmcnt(16)" ::: "memory");
            } else {
                asm volatile("s_waitcnt vmcnt(0)" ::: "memory");
            }
            __builtin_amdgcn_sched_barrier(0);
            unsigned q[8];
#pragma unroll
            for (int j = 0; j < 8; ++j) q[j] = rd(k * 8 + j);
#pragma unroll
            for (int j = 0; j < 8; ++j) bstep(q[j], (j == 3) || (j == 7));
        }
        gerr[b * 128 + lane * 2] = g0;
        gerr[b * 128 + lane * 2 + 1] = g1;
        gerrE[b * 64 + lane] = E;

    } else if (blk < 96) {
        // ---------------- ph forward ----------------
        const int b = blk - 64;
        int t_idx = min(max(ph_il[b] - 1, 0), T - 1);
        const int* tgt = ph_tgt + b * 200;
        float skf[8];
#pragma unroll
        for (int s = 0; s < 8; ++s) {
            int l = lane * 8 + s; float v = 0.f;
            if ((s & 1) && l >= 3 && l <= 400) {
                int i = l >> 1; v = (tgt[i] != tgt[i - 1]) ? 1.f : 0.f;
            }
            skf[s] = v;
        }
        const char* base = (const char*)(Pph + (size_t)b * T * 512);
        float a[8];
#pragma unroll
        for (int s = 0; s < 8; ++s) a[s] = 0.f;
        int E = 0;
        auto rd4 = [&](int row) -> uint4 {
            return *((const uint4*)(ringc + (size_t)(row & 31) * 1024) + lane);
        };
        auto fstep = [&](const uint4& q, bool rn) {
            float p[8]; unpack8(q, p);
            float n7 = dpp_shr1_f(a[7], 0.f), n6 = dpp_shr1_f(a[6], 0.f);
            int En = dpp_shr1_i(E, E);
            int Ep = max(E, En);
            float o[8];
#pragma unroll
            for (int s = 0; s < 8; ++s) o[s] = LDEXPF(a[s], E - Ep);
            float s7 = LDEXPF(n7, En - Ep), s6 = LDEXPF(n6, En - Ep);
            E = Ep;
#pragma unroll
            for (int s = 0; s < 8; ++s) {
                float am1 = (s == 0) ? s7 : o[s - 1];
                float am2 = (s == 0) ? s6 : ((s == 1) ? s7 : o[s - 2]);
                a[s] = __builtin_fmaf(skf[s], am2, o[s] + am1) * p[s];
            }
            if (rn) {
                float m = a[0];
#pragma unroll
                for (int s = 1; s < 8; ++s) m = fmaxf(m, a[s]);
                int k = ((__float_as_int(m) >> 23) & 255) - 127;
#pragma unroll
                for (int s = 0; s < 8; ++s) a[s] = LDEXPF(a[s], -k);
                E += k;
            }
        };

        if (t_idx == T - 1) {
            const char* srcl = base + lane * 16;
#pragma unroll
            for (int r = 0; r < 24; ++r)
                async16(ringc + (size_t)(r & 31) * 1024, srcl + (size_t)r * 1024);
            {
#pragma unroll
                for (int r = 24; r < 32; ++r)
                    async16(ringc + (size_t)(r & 31) * 1024, srcl + (size_t)r * 1024);
                asm volatile("s_waitcnt vmcnt(16)" ::: "memory");
                __builtin_amdgcn_sched_barrier(0);
                uint4 q[8];
#pragma unroll
                for (int j = 0; j < 8; ++j) q[j] = rd4(j);
                float p[8]; unpack8(q[0], p);
#pragma unroll
                for (int s = 0; s < 8; ++s) {
                    int l = lane * 8 + s;
                    a[s] = (l < 2) ? p[s] : 0.f;
                }
                E = 0;
#pragma unroll
                for (int j = 1; j < 8; ++j) fstep(q[j], (j == 3) || (j == 7));
            }
            for (int k = 1; k < NCH; ++k) {
                if (k + 3 < NCH) {
                    int bs = (k + 3) * 8;
#pragma unroll
                    for (int r = 0; r < 8; ++r)
                        async16(ringc + (size_t)((bs + r) & 31) * 1024,
                                srcl + (size_t)(bs + r) * 1024);
                    asm volatile("s_waitcnt vmcnt(16)" ::: "memory");
                } else {
                    asm volatile("s_waitcnt vmcnt(0)" ::: "memory");
                }
                __builtin_amdgcn_sched_barrier(0);
                uint4 q[8];
#pragma unroll
                for (int j = 0; j < 8; ++j) q[j] = rd4(k * 8 + j);
#pragma unroll
                for (int j = 0; j < 8; ++j) fstep(q[j], (j == 3) || (j == 7));
            }
#pragma unroll
            for (int s = 0; s < 8; ++s) aph[b * 512 + lane * 8 + s] = a[s];
            aphE[b * 64 + lane] = E;
        } else {
            // fallback: full forward with capture (direct loads)
            const int L = 401; int tl = ph_tl[b];
            int l1 = min(2 * tl, L - 1), l2 = max(min(2 * tl - 1, L - 1), 0);
            float capA = 0.f, capB = 0.f; int capEA = 0, capEB = 0;
            for (int t = 0; t < T; ++t) {
                uint4 q = *((const uint4*)(base + (size_t)t * 1024) + lane);
                if (t == 0) {
                    float p[8]; unpack8(q, p);
#pragma unroll
                    for (int s = 0; s < 8; ++s) {
                        int l = lane * 8 + s;
                        a[s] = (l < 2) ? p[s] : 0.f;
                    }
                    E = 0;
                } else {
                    fstep(q, false);
                }
                if (t == t_idx) {
#pragma unroll
                    for (int s = 0; s < 8; ++s) {
                        int l = lane * 8 + s;
                        if (l == l1) { capA = a[s]; capEA = E; }
                        if (l == l2) { capB = a[s]; capEB = E; }
                    }
                }
                if ((t & 3) == 3) {
                    float m = a[0];
#pragma unroll
                    for (int s = 1; s < 8; ++s) m = fmaxf(m, a[s]);
                    int k = ((__float_as_int(m) >> 23) & 255) - 127;
#pragma unroll
                    for (int s = 0; s < 8; ++s) a[s] = LDEXPF(a[s], -k);
                    E += k;
                }
            }
            finish_loss(capA, capB, capEA, capEB, lane, loss_ph, b);
        }

    } else {
        // ---------------- ph backward ----------------
        const int b = blk - 96;
        const int* tgt = ph_tgt + b * 200;
        const int L = 401; int tl = ph_tl[b];
        int l1 = min(2 * tl, L - 1), l2 = max(min(2 * tl - 1, L - 1), 0);
        float skf[8];
#pragma unroll
        for (int s = 0; s < 8; ++s) {
            int l = lane * 8 + s; float v = 0.f;
            if ((s & 1) && l >= 3 && l <= 400) {
                int i = l >> 1; v = (tgt[i] != tgt[i - 1]) ? 1.f : 0.f;
            }
            skf[s] = v;
        }
        float nskf1 = dpp_shl1_f(skf[1], 0.f);
        float skp2[8];
        skp2[0] = 0.f; skp2[1] = skf[3]; skp2[2] = 0.f; skp2[3] = skf[5];
        skp2[4] = 0.f; skp2[5] = skf[7]; skp2[6] = 0.f; skp2[7] = nskf1;

        const char* base = (const char*)(Pph + (size_t)b * T * 512);
        const char* srcl = base + (size_t)(T - 1) * 1024 + lane * 16;  // row u: -u*1024
        auto rd4 = [&](int row) -> uint4 {
            return *((const uint4*)(ringc + (size_t)(row & 31) * 1024) + lane);
        };
        float g[8];
#pragma unroll
        for (int s = 0; s < 8; ++s) g[s] = 0.f;
        int E = 0;
        auto bstep = [&](const uint4& q, bool rn) {
            float p[8]; unpack8(q, p);
            float nb0 = dpp_shl1_f(g[0], 0.f), nb1 = dpp_shl1_f(g[1], 0.f);
            int En = dpp_shl1_i(E, E);
            int Ep = max(E, En);
            float o[8];
#pragma unroll
            for (int s = 0; s < 8; ++s) o[s] = LDEXPF(g[s], E - Ep);
            float t0 = LDEXPF(nb0, En - Ep), t1 = LDEXPF(nb1, En - Ep);
            E = Ep;
#pragma unroll
            for (int s = 0; s < 8; ++s) {
                float bp1 = (s < 7) ? o[s + 1] : t0;
                float bp2 = (s < 6) ? o[s + 2] : ((s == 6) ? t0 : t1);
                g[s] = __builtin_fmaf(skp2[s], bp2, o[s] + bp1) * p[s];
            }
            if (rn) {
                float m = g[0];
#pragma unroll
                for (int s = 1; s < 8; ++s) m = fmaxf(m, g[s]);
                int k = ((__float_as_int(m) >> 23) & 255) - 127;
#pragma unroll
                for (int s = 0; s < 8; ++s) g[s] = LDEXPF(g[s], -k);
                E += k;
            }
        };
#pragma unroll
        for (int r = 0; r < 24; ++r)
            async16(ringc + (size_t)(r & 31) * 1024, srcl - (size_t)r * 1024);
        {
#pragma unroll
            for (int r = 24; r < 32; ++r)
                async16(ringc + (size_t)(r & 31) * 1024, srcl - (size_t)r * 1024);
            asm volatile("s_waitcnt vmcnt(16)" ::: "memory");
            __builtin_amdgcn_sched_barrier(0);
            uint4 q[8];
#pragma unroll
            for (int j = 0; j < 8; ++j) q[j] = rd4(j);
            float p[8]; unpack8(q[0], p);
#pragma unroll
            for (int s = 0; s < 8; ++s) {
                int l = lane * 8 + s;
                g[s] = (l == l1 || l == l2) ? p[s] : 0.f;
            }
            E = 0;
#pragma unroll
            for (int j = 1; j < 8; ++j) bstep(q[j], (j == 3) || (j == 7));
        }
        for (int k = 1; k < NCH; ++k) {
            if (k + 3 < NCH) {
                int bs = (k + 3) * 8;
#pragma unroll
                for (int r = 0; r < 8; ++r)
                    async16(ringc + (size_t)((bs + r) & 31) * 1024,
                            srcl - (size_t)(bs + r) * 1024);
                asm volatile("s_waitcnt vmcnt(16)" ::: "memory");
            } else {
                asm volatile("s_waitcnt vmcnt(0)" ::: "memory");
            }
            __builtin_amdgcn_sched_barrier(0);
            uint4 q[8];
#pragma unroll
            for (int j = 0; j < 8; ++j) q[j] = rd4(k * 8 + j);
#pragma unroll
            for (int j = 0; j < 8; ++j) bstep(q[j], (j == 3) || (j == 7));
        }
#pragma unroll
        for (int s = 0; s < 8; ++s) gph[b * 512 + lane * 8 + s] = g[s];
        gphE[b * 64 + lane] = E;
    }
}

// ===========================================================================
// combine: p = sum_l alpha_tm[l] * (g[l] + g[l+1] + allow[l+2]*g[l+2])
// 64 blocks x 64 threads; block<32 = err sample, else ph sample.
// ===========================================================================
__global__ __launch_bounds__(64) void combine_kernel(
    const int* __restrict__ err_tgt, const int* __restrict__ ph_tgt,
    const int* __restrict__ err_il, const int* __restrict__ ph_il,
    const float* __restrict__ aerr, const int* __restrict__ aerrE,
    const float* __restrict__ gerr, const int* __restrict__ gerrE,
    const float* __restrict__ aph, const int* __restrict__ aphE,
    const float* __restrict__ gph, const int* __restrict__ gphE,
    float* __restrict__ loss_err, float* __restrict__ loss_ph, int T) {
    const int blk = blockIdx.x;
    const int lane = threadIdx.x & 63;
    if (blk < 32) {
        const int b = blk;
        int t_idx = min(max(err_il[b] - 1, 0), T - 1);
        if (t_idx != T - 1) return;   // loss already written by fwd fallback
        const int* tgt = err_tgt + b * 50;
        float skip1f;
        {
            int l = lane * 2 + 1; bool sk = false;
            if (l >= 3 && l <= 100) { int i = l >> 1; sk = (tgt[i] != tgt[i - 1]); }
            skip1f = sk ? 1.f : 0.f;
        }
        float a0 = aerr[b * 128 + lane * 2], a1 = aerr[b * 128 + lane * 2 + 1];
        int Ea = aerrE[b * 64 + lane];
        float g0 = gerr[b * 128 + lane * 2], g1 = gerr[b * 128 + lane * 2 + 1];
        int Eb = gerrE[b * 64 + lane];
        float nb0 = __shfl_down(g0, 1), nb1 = __shfl_down(g1, 1);
        int Ebn = __shfl_down(Eb, 1);
        float skp2 = __shfl_down(skip1f, 1);
        if (lane == 63) { nb0 = 0.f; nb1 = 0.f; Ebn = Eb; skp2 = 0.f; }
        int Em = max(Eb, Ebn);
        float o0 = LDEXPF(g0, Eb - Em), o1 = LDEXPF(g1, Eb - Em);
        float t0 = LDEXPF(nb0, Ebn - Em), t1 = LDEXPF(nb1, Ebn - Em);
        float bc0 = o0 + o1;
        float bc1 = __builtin_fmaf(skp2, t1, o1 + t0);
        float dot = __builtin_fmaf(a0, bc0, a1 * bc1);
        float v = (dot > 0.f) ? (float)(Ea + Em) + LOG2F(dot) : NEG2;
        float mm = v;
#pragma unroll
        for (int i = 1; i < 64; i <<= 1) mm = fmaxf(mm, __shfl_xor(mm, i));
        float sum = EXP2F(v - mm);
#pragma unroll
        for (int i = 1; i < 64; i <<= 1) sum += __shfl_xor(sum, i);
        if (lane == 0) loss_err[b] = -(mm + LOG2F(sum)) * LN2;
    } else {
        const int b = blk - 32;
        int t_idx = min(max(ph_il[b] - 1, 0), T - 1);
        if (t_idx != T - 1) return;
        const int* tgt = ph_tgt + b * 200;
        float skf[8];
#pragma unroll
        for (int s = 0; s < 8; ++s) {
            int l = lane * 8 + s; float v = 0.f;
            if ((s & 1) && l >= 3 && l <= 400) {
                int i = l >> 1; v = (tgt[i] != tgt[i - 1]) ? 1.f : 0.f;
            }
            skf[s] = v;
        }
        float a[8], g[8];
#pragma unroll
        for (int s = 0; s < 8; ++s) {
            a[s] = aph[b * 512 + lane * 8 + s];
            g[s] = gph[b * 512 + lane * 8 + s];
        }
        int Ea = aphE[b * 64 + lane];
        int Eb = gphE[b * 64 + lane];
        float nb0 = __shfl_down(g[0], 1), nb1 = __shfl_down(g[1], 1);
        int Ebn = __shfl_down(Eb, 1);
        float nskf1 = __shfl_down(skf[1], 1);
        if (lane == 63) { nb0 = 0.f; nb1 = 0.f; Ebn = Eb; nskf1 = 0.f; }
        float skp2[8];
        skp2[0] = 0.f; skp2[1] = skf[3]; skp2[2] = 0.f; skp2[3] = skf[5];
        skp2[4] = 0.f; skp2[5] = skf[7]; skp2[6] = 0.f; skp2[7] = nskf1;
        int Em = max(Eb, Ebn);
        float o[8];
#pragma unroll
        for (int s = 0; s < 8; ++s) o[s] = LDEXPF(g[s], Eb - Em);
        float t0 = LDEXPF(nb0, Ebn - Em), t1 = LDEXPF(nb1, Ebn - Em);
        float dot = 0.f;
#pragma unroll
        for (int s = 0; s < 8; ++s) {
            float bp1 = (s < 7) ? o[s + 1] : t0;
            float bp2 = (s < 6) ? o[s + 2] : ((s == 6) ? t0 : t1);
            float bc = __builtin_fmaf(skp2[s], bp2, o[s] + bp1);
            dot = __builtin_fmaf(a[s], bc, dot);
        }
        float v = (dot > 0.f) ? (float)(Ea + Em) + LOG2F(dot) : NEG2;
        float mm = v;
#pragma unroll
        for (int i = 1; i < 64; i <<= 1) mm = fmaxf(mm, __shfl_xor(mm, i));
        float sum = EXP2F(v - mm);
#pragma unroll
        for (int i = 1; i < 64; i <<= 1) sum += __shfl_xor(sum, i);
        if (lane == 0) loss_ph[b] = -(mm + LOG2F(sum)) * LN2;
    }
}

// ===========================================================================
// FALLBACK PATH (round-5, proven) — used only if ws_size too small
// ===========================================================================
__global__ void denom_err_kernel(const float* __restrict__ logits,
                                 float* __restrict__ d2, int rows) {
    int r = blockIdx.x * blockDim.x + threadIdx.x;
    if (r >= rows) return;
    const float* row = logits + (size_t)r * 8;
    float x[8];
#pragma unroll
    for (int i = 0; i < 8; ++i) x[i] = row[i] * LOG2E;
    float m = x[0];
#pragma unroll
    for (int i = 1; i < 8; ++i) m = fmaxf(m, x[i]);
    float s = 0.f;
#pragma unroll
    for (int i = 0; i < 8; ++i) s += EXP2F(x[i] - m);
    d2[r] = m + LOG2F(s);
}

__global__ void denom_ph_kernel(const float* __restrict__ logits,
                                float* __restrict__ d2, int rows) {
    int wave = (int)((blockIdx.x * (size_t)blockDim.x + threadIdx.x) >> 6);
    int lane = threadIdx.x & 63;
    if (wave >= rows) return;
    const float* row = logits + (size_t)wave * 128;
    float x0 = row[lane] * LOG2E;
    float x1 = row[lane + 64] * LOG2E;
    float m = fmaxf(x0, x1);
#pragma unroll
    for (int i = 1; i < 64; i <<= 1) m = fmaxf(m, __shfl_xor(m, i));
    float s = EXP2F(x0 - m) + EXP2F(x1 - m);
#pragma unroll
    for (int i = 1; i < 64; i <<= 1) s += __shfl_xor(s, i);
    if (lane == 0) d2[wave] = m + LOG2F(s);
}

template <int NST, int C>
__device__ __forceinline__ void gather_row(const float* ringL, const float* ringD,
                                           int row, const int (&clsoff)[NST],
                                           float (&g)[NST], float& gd) {
    int base = (row & 63) * C;
#pragma unroll
    for (int s = 0; s < NST; ++s) g[s] = ringL[base + clsoff[s]];
    gd = ringD[row & 63];
}

template <int C, int CHV>
__device__ __forceinline__ void stage_load(const float* __restrict__ lrow,
                                           const float* __restrict__ d2row,
                                           int t0, int T, int lane,
                                           float4 (&st)[CHV], float4& stD) {
#pragma unroll
    for (int j = 0; j < CHV; ++j) {
        int e = t0 * C + (j * 64 + lane) * 4;
        e = min(e, T * C - 4);
        st[j] = *(const float4*)(lrow + e);
    }
    if (lane < 8) {
        int e = t0 + lane * 4;
        e = min(e, T - 4);
        stD = *(const float4*)(d2row + e);
    }
}

template <int C, int CHV>
__device__ __forceinline__ void stage_write(float* ringL, float* ringD, int t0, int lane,
                                            const float4 (&st)[CHV], const float4& stD) {
    int base = (t0 & 63) * C;
#pragma unroll
    for (int j = 0; j < CHV; ++j)
        *(float4*)(ringL + base + (j * 64 + lane) * 4) = st[j];
    if (lane < 8)
        *(float4*)(ringD + (t0 & 63) + lane * 4) = stD;
}

template <int NST>
__device__ __forceinline__ void do_step_lin(
    float (&a)[NST], int& E,
    const float (&g)[NST], float gd,
    const float (&validf)[NST], const bool (&skipb)[NST],
    int lane, int t, int t_idx, int l1, int l2,
    float& capA, float& capB, int& capEA, int& capEB) {
    float p[NST];
#pragma unroll
    for (int s = 0; s < NST; ++s)
        p[s] = validf[s] * EXP2F(__builtin_fmaf(g[s], LOG2E, -gd));
    if (t == 0) {
#pragma unroll
        for (int s = 0; s < NST; ++s) {
            int l = lane * NST + s;
            a[s] = (l < 2) ? p[s] : 0.f;
        }
        E = 0;
    } else {
        float top1 = dpp_shr1_f(a[NST - 1], 0.f);
        int   En   = dpp_shr1_i(E, E);
        int Ep = max(E, En);
        float t1 = LDEXPF(top1, En - Ep);
        float ao[NST];
#pragma unroll
        for (int s = 0; s < NST; ++s) ao[s] = LDEXPF(a[s], E - Ep);
        E = Ep;
#pragma unroll
        for (int s = 0; s < NST; ++s) {
            float sum;
            if (s == 0)            sum = ao[0] + t1;
            else if (s == 1)       sum = ao[1] + ao[0] + (skipb[1] ? t1 : 0.f);
            else if ((s & 1) == 0) sum = ao[s] + ao[s - 1];
            else                   sum = ao[s] + ao[s - 1] + (skipb[s] ? ao[s - 2] : 0.f);
            a[s] = sum * p[s];
        }
    }
    if (t == t_idx) {
#pragma unroll
        for (int s = 0; s < NST; ++s) {
            int l = lane * NST + s;
            if (l == l1) { capA = a[s]; capEA = E; }
            if (l == l2) { capB = a[s]; capEB = E; }
        }
    }
    if ((t & 1) == 1) {
        float m = a[0];
#pragma unroll
        for (int s = 1; s < NST; ++s) m = fmaxf(m, a[s]);
        int k = ((__float_as_int(m) >> 23) & 255) - 127;
#pragma unroll
        for (int s = 0; s < NST; ++s) a[s] = LDEXPF(a[s], -k);
        E += k;
    }
}

template <int NST, int C, int S, int CHV>
__device__ __forceinline__ void ctc_run(
    const float* __restrict__ lrow, const float* __restrict__ d2row,
    const int* __restrict__ tgt, int T, int t_idx, int l1, int l2,
    float* ringL, float* ringD, float* __restrict__ loss_out, int b) {
    const int lane = threadIdx.x & 63;
    const int L = 2 * S + 1;
    int clsoff[NST];
    bool skipb[NST];
    float validf[NST];
#pragma unroll
    for (int s = 0; s < NST; ++s) {
        int l = lane * NST + s;
        bool v = (l < L);
        int li = v ? l : 0;
        int c = 0;
        bool sk = false;
        if (li & 1) {
            int i = li >> 1;
            c = tgt[i];
            if (li >= 3) sk = (c != tgt[i - 1]);
        }
        clsoff[s] = c;
        skipb[s] = sk;
        validf[s] = v ? 1.f : 0.f;
    }
    float4 st[CHV];
    float4 stD = make_float4(0.f, 0.f, 0.f, 0.f);
    stage_load<C, CHV>(lrow, d2row, 0, T, lane, st, stD);
    stage_write<C, CHV>(ringL, ringD, 0, lane, st, stD);
    stage_load<C, CHV>(lrow, d2row, 32, T, lane, st, stD);
    stage_write<C, CHV>(ringL, ringD, 32, lane, st, stD);
    stage_load<C, CHV>(lrow, d2row, 64, T, lane, st, stD);
    float gA[NST], gB[NST], dA, dB;
    gather_row<NST, C>(ringL, ringD, 0, clsoff, gA, dA);
    gather_row<NST, C>(ringL, ringD, 1, clsoff, gB, dB);
    float a[NST];
#pragma unroll
    for (int s = 0; s < NST; ++s) a[s] = 0.f;
    int E = 0;
    float capA = 0.f, capB = 0.f;
    int capEA = 0, capEB = 0;
    const int NCH = (T + 31) >> 5;
    for (int c = 0; c < NCH; ++c) {
        int t0 = c << 5;
        int half = min(32, T - t0) >> 1;
        for (int j = 0; j < half; ++j) {
            int t = t0 + 2 * j;
            do_step_lin<NST>(a, E, gA, dA, validf, skipb, lane, t, t_idx, l1, l2,
                             capA, capB, capEA, capEB);
            gather_row<NST, C>(ringL, ringD, t + 2, clsoff, gA, dA);
            do_step_lin<NST>(a, E, gB, dB, validf, skipb, lane, t + 1, t_idx, l1, l2,
                             capA, capB, capEA, capEB);
            gather_row<NST, C>(ringL, ringD, t + 3, clsoff, gB, dB);
            if (j == 14 && c + 2 < NCH) {
                stage_write<C, CHV>(ringL, ringD, t0 + 64, lane, st, stD);
                if (c + 3 < NCH)
                    stage_load<C, CHV>(lrow, d2row, t0 + 96, T, lane, st, stD);
            }
        }
    }
    float vA = (capA > 0.f) ? (float)capEA + LOG2F(capA) : NEG2;
    float vB = (capB > 0.f) ? (float)capEB + LOG2F(capB) : NEG2;
    float mm = fmaxf(vA, vB);
#pragma unroll
    for (int i = 1; i < 64; i <<= 1) mm = fmaxf(mm, __shfl_xor(mm, i));
    float sum = EXP2F(vA - mm) + EXP2F(vB - mm);
#pragma unroll
    for (int i = 1; i < 64; i <<= 1) sum += __shfl_xor(sum, i);
    if (lane == 0) loss_out[b] = -(mm + LOG2F(sum)) * LN2;
}

__global__ __launch_bounds__(64) void ctc_kernel(
    const float* __restrict__ err_logits, const float* __restrict__ ph_logits,
    const int* __restrict__ err_tgt, const int* __restrict__ ph_tgt,
    const int* __restrict__ err_il, const int* __restrict__ ph_il,
    const int* __restrict__ err_tl, const int* __restrict__ ph_tl,
    const float* __restrict__ d2_err, const float* __restrict__ d2_ph,
    float* __restrict__ loss_err, float* __restrict__ loss_ph, int T) {
    __shared__ float ringL[64 * 128];
    __shared__ float ringD[64];
    int blk = blockIdx.x;
    if (blk < 32) {
        int b = blk;
        const int L = 101;
        int tl = err_tl[b];
        int l1 = min(2 * tl, L - 1);
        int l2 = max(min(2 * tl - 1, L - 1), 0);
        int t_idx = min(max(err_il[b] - 1, 0), T - 1);
        ctc_run<2, 8, 50, 1>(err_logits + (size_t)b * T * 8, d2_err + (size_t)b * T,
                             err_tgt + b * 50, T, t_idx, l1, l2, ringL, ringD,
                             loss_err, b);
    } else {
        int b = blk - 32;
        const int L = 401;
        int tl = ph_tl[b];
        int l1 = min(2 * tl, L - 1);
        int l2 = max(min(2 * tl - 1, L - 1), 0);
        int t_idx = min(max(ph_il[b] - 1, 0), T - 1);
        ctc_run<8, 128, 200, 16>(ph_logits + (size_t)b * T * 128, d2_ph + (size_t)b * T,
                                 ph_tgt + b * 200, T, t_idx, l1, l2, ringL, ringD,
                                 loss_ph, b);
    }
}

// ---------------------------------------------------------------------------
// Final: focal transform + means + total. One wave.
// ---------------------------------------------------------------------------
__global__ void final_kernel(const float* __restrict__ loss_err,
                             const float* __restrict__ loss_ph,
                             float* __restrict__ out) {
    int lane = threadIdx.x & 63;
    float fe = 0.f, fp = 0.f;
    if (lane < 32) {
        float l = fmaxf(loss_err[lane], 1e-6f);
        float pt = fminf(fmaxf(EXP2F(-l * LOG2E), 1e-6f), 1.0f);
        float om = 1.f - pt;
        fe = om * om * l;
        l = fmaxf(loss_ph[lane], 1e-6f);
        pt = fminf(fmaxf(EXP2F(-l * LOG2E), 1e-6f), 1.0f);
        om = 1.f - pt;
        fp = om * om * l;
    }
#pragma unroll
    for (int i = 1; i < 64; i <<= 1) {
        fe += __shfl_xor(fe, i);
        fp += __shfl_xor(fp, i);
    }
    if (lane == 0) {
        float err = fe / 32.f;
        float ph = fp / 32.f;
        out[0] = err + ph;
        out[1] = err;
        out[2] = ph;
    }
}

// ---------------------------------------------------------------------------
extern "C" void kernel_launch(void* const* d_in, const int* in_sizes, int n_in,
                              void* d_out, int out_size, void* d_ws, size_t ws_size,
                              hipStream_t stream) {
    const int B = 32, T = 2000;
    const float* err_logits = (const float*)d_in[0];  // [32,2000,8]
    const float* ph_logits  = (const float*)d_in[1];  // [32,2000,128]
    const int* err_tgt = (const int*)d_in[2];         // [32,50]
    const int* ph_tgt  = (const int*)d_in[3];         // [32,200]
    const int* err_il  = (const int*)d_in[4];
    const int* ph_il   = (const int*)d_in[5];
    const int* err_tl  = (const int*)d_in[6];
    const int* ph_tl   = (const int*)d_in[7];
    float* out = (float*)d_out;

    const size_t PH_US  = (size_t)B * T * 512;   // ushorts
    const size_t ERR_US = (size_t)B * T * 128;   // ushorts

    char* p = (char*)d_ws;
    unsigned short* Pph  = (unsigned short*)p; p += PH_US * 2;
    unsigned short* Perr = (unsigned short*)p; p += ERR_US * 2;
    float* aph  = (float*)p; p += (size_t)B * 512 * 4;
    int*   aphE = (int*)p;   p += (size_t)B * 64 * 4;
    float* gph  = (float*)p; p += (size_t)B * 512 * 4;
    int*   gphE = (int*)p;   p += (size_t)B * 64 * 4;
    float* aerr = (float*)p; p += (size_t)B * 128 * 4;
    int*   aerrE= (int*)p;   p += (size_t)B * 64 * 4;
    float* gerr = (float*)p; p += (size_t)B * 128 * 4;
    int*   gerrE= (int*)p;   p += (size_t)B * 64 * 4;
    float* loss_err = (float*)p; p += B * 4;
    float* loss_ph  = (float*)p; p += B * 4;
    const size_t need = (size_t)(p - (char*)d_ws);

    if (ws_size >= need) {
        // -------- fast path: probs -> fwd/bwd ctc -> combine -> final --------
        ph_prob_kernel<<<(B * T) / 4, 256, 0, stream>>>(ph_logits, ph_tgt, Pph);
        err_prob_kernel<<<(B * T) / 4, 256, 0, stream>>>(err_logits, err_tgt, Perr);
        ctc6_kernel<<<128, 64, 0, stream>>>(Perr, Pph, err_tgt, ph_tgt,
                                            err_il, ph_il, err_tl, ph_tl,
                                            aerr, aerrE, gerr, gerrE,
                                            aph, aphE, gph, gphE,
                                            loss_err, loss_ph, T);
        combine_kernel<<<64, 64, 0, stream>>>(err_tgt, ph_tgt, err_il, ph_il,
                                              aerr, aerrE, gerr, gerrE,
                                              aph, aphE, gph, gphE,
                                              loss_err, loss_ph, T);
        final_kernel<<<1, 64, 0, stream>>>(loss_err, loss_ph, out);
    } else {
        // -------- fallback (round-5) --------
        float* ws = (float*)d_ws;
        float* d2_err   = ws;
        float* d2_ph    = ws + 64000;
        float* le = ws + 128000;
        float* lp = ws + 128032;
        int rows = B * T;
        denom_err_kernel<<<(rows + 255) / 256, 256, 0, stream>>>(err_logits, d2_err, rows);
        denom_ph_kernel<<<rows / 4, 256, 0, stream>>>(ph_logits, d2_ph, rows);
        ctc_kernel<<<64, 64, 0, stream>>>(err_logits, ph_logits, err_tgt, ph_tgt,
                                          err_il, ph_il, err_tl, ph_tl,
                                          d2_err, d2_ph, le, lp, T);
        final_kernel<<<1, 64, 0, stream>>>(le, lp, out);
    }
}

// Round 11
// 167.799 us; speedup vs baseline: 2.3385x; 1.0992x over previous
//
#include <hip/hip_runtime.h>
#include <hip/hip_bf16.h>

#define LOG2E 1.4426950408889634f
#define LN2   0.6931471805599453f
#define NEG2  (-1.4426950e30f)
#define EXP2F(x) __builtin_exp2f(x)
#define LOG2F(x) __builtin_log2f(x)
#define LDEXPF(x,k) __builtin_ldexpf((x),(k))

// DPP whole-wave shifts. shr: lane i <- lane i-1 (lane0 gets old).
//                        shl: lane i <- lane i+1 (lane63 gets old).
__device__ __forceinline__ float dpp_shr1_f(float x, float old) {
    return __int_as_float(__builtin_amdgcn_update_dpp(
        __float_as_int(old), __float_as_int(x), 0x138, 0xF, 0xF, false));
}
__device__ __forceinline__ int dpp_shr1_i(int x, int old) {
    return __builtin_amdgcn_update_dpp(old, x, 0x138, 0xF, 0xF, false);
}
__device__ __forceinline__ float dpp_shl1_f(float x, float old) {
    return __int_as_float(__builtin_amdgcn_update_dpp(
        __float_as_int(old), __float_as_int(x), 0x130, 0xF, 0xF, false));
}
__device__ __forceinline__ int dpp_shl1_i(int x, int old) {
    return __builtin_amdgcn_update_dpp(old, x, 0x130, 0xF, 0xF, false);
}

__device__ __forceinline__ unsigned bf16r(float x) {
    return (__float_as_uint(x) + 0x8000u) >> 16;
}

__device__ __forceinline__ void async16(void* lds, const void* g) {
    __builtin_amdgcn_global_load_lds(
        (const __attribute__((address_space(1))) unsigned int*)g,
        (__attribute__((address_space(3))) unsigned int*)lds, 16, 0, 0);
}
__device__ __forceinline__ void async4(void* lds, const void* g) {
    __builtin_amdgcn_global_load_lds(
        (const __attribute__((address_space(1))) unsigned int*)g,
        (__attribute__((address_space(3))) unsigned int*)lds, 4, 0, 0);
}

__device__ __forceinline__ void unpack8(const uint4& q, float (&p)[8]) {
    p[0] = __uint_as_float(q.x << 16);
    p[1] = __uint_as_float(q.x & 0xFFFF0000u);
    p[2] = __uint_as_float(q.y << 16);
    p[3] = __uint_as_float(q.y & 0xFFFF0000u);
    p[4] = __uint_as_float(q.z << 16);
    p[5] = __uint_as_float(q.z & 0xFFFF0000u);
    p[6] = __uint_as_float(q.w << 16);
    p[7] = __uint_as_float(q.w & 0xFFFF0000u);
}

// ===========================================================================
// Fused emission-probability precompute: blocks [0,16000) = ph, rest = err.
// ===========================================================================
__global__ __launch_bounds__(256) void prob_kernel(
    const float* __restrict__ ph_logits, const int* __restrict__ ph_tgt,
    unsigned short* __restrict__ Pph,
    const float* __restrict__ err_logits, const int* __restrict__ err_tgt,
    unsigned short* __restrict__ Perr) {
    int wid = threadIdx.x >> 6, lane = threadIdx.x & 63;
    __shared__ float ylds[4][128];
    if (blockIdx.x < 16000) {
        int r = blockIdx.x * 4 + wid;               // [0, 64000)
        int b = r / 2000;
        const float* row = ph_logits + (size_t)r * 128;
        float y0 = row[lane] * LOG2E;
        float y1 = row[lane + 64] * LOG2E;
        ylds[wid][lane] = y0;
        ylds[wid][lane + 64] = y1;
        float m = fmaxf(y0, y1);
#pragma unroll
        for (int i = 1; i < 64; i <<= 1) m = fmaxf(m, __shfl_xor(m, i));
        float s = EXP2F(y0 - m) + EXP2F(y1 - m);
#pragma unroll
        for (int i = 1; i < 64; i <<= 1) s += __shfl_xor(s, i);
        float d2 = m + LOG2F(s);

        int c[4];
#pragma unroll
        for (int k = 0; k < 4; ++k) {
            int i = min(4 * lane + k, 199);
            c[k] = ph_tgt[b * 200 + i];
        }
        float pb = EXP2F(ylds[wid][0] - d2);
        float po[4];
#pragma unroll
        for (int k = 0; k < 4; ++k) po[k] = EXP2F(ylds[wid][c[k]] - d2);

        unsigned h[8];
#pragma unroll
        for (int s2 = 0; s2 < 8; ++s2) {
            int l = 8 * lane + s2;
            float v = (s2 & 1) ? po[s2 >> 1] : pb;
            h[s2] = (l <= 400) ? bf16r(v) : 0u;
        }
        uint4 u;
        u.x = h[0] | (h[1] << 16);
        u.y = h[2] | (h[3] << 16);
        u.z = h[4] | (h[5] << 16);
        u.w = h[6] | (h[7] << 16);
        *(uint4*)(Pph + (size_t)r * 512 + lane * 8) = u;
    } else {
        int r = (blockIdx.x - 16000) * 4 + wid;
        int b = r / 2000;
        const float* row = err_logits + (size_t)r * 8;
        float y = (lane < 8) ? row[lane] * LOG2E : -3.0e38f;
        if (lane < 8) ylds[wid][lane] = y;
        float m = y;
#pragma unroll
        for (int i = 1; i < 64; i <<= 1) m = fmaxf(m, __shfl_xor(m, i));
        float s = EXP2F(y - m);
#pragma unroll
        for (int i = 1; i < 64; i <<= 1) s += __shfl_xor(s, i);
        float d2 = m + LOG2F(s);

        int cc = err_tgt[b * 50 + min(lane, 49)];
        float pb = EXP2F(ylds[wid][0] - d2);
        float pod = EXP2F(ylds[wid][cc] - d2);
        int l0 = 2 * lane;
        unsigned h0 = (l0 <= 100) ? bf16r(pb) : 0u;
        unsigned h1 = (l0 + 1 <= 100) ? bf16r(pod) : 0u;
        *(unsigned*)(Perr + (size_t)r * 128 + lane * 2) = h0 | (h1 << 16);
    }
}

// ===========================================================================
// Shared helpers
// ===========================================================================
__device__ __forceinline__ void finish_loss(float capA, float capB, int capEA,
                                            int capEB, int lane,
                                            float* __restrict__ loss_out, int b) {
    float vA = (capA > 0.f) ? (float)capEA + LOG2F(capA) : NEG2;
    float vB = (capB > 0.f) ? (float)capEB + LOG2F(capB) : NEG2;
    float mm = fmaxf(vA, vB);
#pragma unroll
    for (int i = 1; i < 64; i <<= 1) mm = fmaxf(mm, __shfl_xor(mm, i));
    float sum = EXP2F(vA - mm) + EXP2F(vB - mm);
#pragma unroll
    for (int i = 1; i < 64; i <<= 1) sum += __shfl_xor(sum, i);
    if (lane == 0) loss_out[b] = -(mm + LOG2F(sum)) * LN2;
}

// ===========================================================================
// ctc7: fwd/bwd split with period-constant neighbor scale factor f.
// E changes only at renorm (every 4 steps); the cross-lane exponent exchange
// happens once per period: Ep=max(E,En), own mantissas adopt Ep, f=2^(En-Ep)
// (exact power of two, f<=1 => no overflow). Per-step alignment = 2 dpp+2 mul.
// ===========================================================================
__global__ __launch_bounds__(64) void ctc7_kernel(
    const unsigned short* __restrict__ Perr, const unsigned short* __restrict__ Pph,
    const int* __restrict__ err_tgt, const int* __restrict__ ph_tgt,
    const int* __restrict__ err_il, const int* __restrict__ ph_il,
    const int* __restrict__ err_tl, const int* __restrict__ ph_tl,
    float* __restrict__ aerr, int* __restrict__ aerrE,
    float* __restrict__ gerr, int* __restrict__ gerrE,
    float* __restrict__ aph, int* __restrict__ aphE,
    float* __restrict__ gph, int* __restrict__ gphE,
    float* __restrict__ loss_err, float* __restrict__ loss_ph, int T) {
    __shared__ unsigned short ring[32 * 512];
    char* ringc = (char*)ring;
    const int blk = blockIdx.x;
    const int lane = threadIdx.x & 63;
    const int NR = T >> 1;          // 1000
    const int NCH = NR >> 3;        // 125

    if (blk < 32) {
        // ---------------- err forward ----------------
        const int b = blk;
        int t_idx = min(max(err_il[b] - 1, 0), T - 1);
        const int* tgt = err_tgt + b * 50;
        float skip1f;
        {
            int l = lane * 2 + 1; bool sk = false;
            if (l >= 3 && l <= 100) { int i = l >> 1; sk = (tgt[i] != tgt[i - 1]); }
            skip1f = sk ? 1.f : 0.f;
        }
        const char* base = (const char*)(Perr + (size_t)b * T * 128);
        float a0 = 0.f, a1 = 0.f; int E = 0; float f = 1.f;

        auto fstep = [&](unsigned cur) {
            float p0 = __uint_as_float(cur << 16);
            float p1 = __uint_as_float(cur & 0xFFFF0000u);
            float t1 = dpp_shr1_f(a1, 0.f) * f;
            float na0 = (a0 + t1) * p0;
            a1 = __builtin_fmaf(skip1f, t1, a1 + a0) * p1;
            a0 = na0;
        };
        auto rex = [&]() {
            float m = fmaxf(a0, a1);
            int k = ((__float_as_int(m) >> 23) & 255) - 127;
            a0 = LDEXPF(a0, -k); a1 = LDEXPF(a1, -k); E += k;
            int En = dpp_shr1_i(E, E);
            int Ep = max(E, En);
            int eo = E - Ep;
            a0 = LDEXPF(a0, eo); a1 = LDEXPF(a1, eo);
            E = Ep;
            int d = max(En - Ep, -127);
            f = __int_as_float((d + 127) << 23);
        };

        if (t_idx == T - 1) {
            const char* srcl = base + lane * 4;
            auto rd = [&](int row) -> unsigned {
                return *((const unsigned*)(ringc + (size_t)(row & 31) * 256) + lane);
            };
#pragma unroll
            for (int r = 0; r < 24; ++r)
                async4(ringc + (size_t)(r & 31) * 256, srcl + (size_t)r * 256);
            {   // chunk 0: init at t=0
#pragma unroll
                for (int r = 24; r < 32; ++r)
                    async4(ringc + (size_t)(r & 31) * 256, srcl + (size_t)r * 256);
                asm volatile("s_waitcnt vmcnt(16)" ::: "memory");
                __builtin_amdgcn_sched_barrier(0);
                unsigned q[8];
#pragma unroll
                for (int j = 0; j < 8; ++j) q[j] = rd(j);
                float p0 = __uint_as_float(q[0] << 16);
                float p1 = __uint_as_float(q[0] & 0xFFFF0000u);
                a0 = (lane == 0) ? p0 : 0.f;
                a1 = (lane == 0) ? p1 : 0.f;
                E = 0; f = 1.f;
#pragma unroll
                for (int j = 1; j < 8; ++j) {
                    fstep(q[j]);
                    if (j == 3 || j == 7) rex();
                }
            }
            for (int k = 1; k < NCH; ++k) {
                if (k + 3 < NCH) {
                    int bs = (k + 3) * 8;
#pragma unroll
                    for (int r = 0; r < 8; ++r)
                        async4(ringc + (size_t)((bs + r) & 31) * 256,
                               srcl + (size_t)(bs + r) * 256);
                    asm volatile("s_waitcnt vmcnt(16)" ::: "memory");
                } else {
                    asm volatile("s_waitcnt vmcnt(0)" ::: "memory");
                }
                __builtin_amdgcn_sched_barrier(0);
                unsigned q[8];
#pragma unroll
                for (int j = 0; j < 8; ++j) q[j] = rd(k * 8 + j);
#pragma unroll
                for (int j = 0; j < 8; ++j) {
                    fstep(q[j]);
                    if (j == 3 || j == 7) rex();
                }
            }
            aerr[b * 128 + lane * 2] = a0;
            aerr[b * 128 + lane * 2 + 1] = a1;
            aerrE[b * 64 + lane] = E;
        } else {
            // fallback: full forward with capture + per-step alignment (rare)
            const int L = 101; int tl = err_tl[b];
            int l1 = min(2 * tl, L - 1), l2 = max(min(2 * tl - 1, L - 1), 0);
            float capA = 0.f, capB = 0.f; int capEA = 0, capEB = 0;
            for (int t = 0; t < T; ++t) {
                unsigned cur = *((const unsigned*)(base + (size_t)t * 256) + lane);
                float p0 = __uint_as_float(cur << 16);
                float p1 = __uint_as_float(cur & 0xFFFF0000u);
                if (t == 0) {
                    a0 = (lane == 0) ? p0 : 0.f;
                    a1 = (lane == 0) ? p1 : 0.f;
                    E = 0;
                } else {
                    float n1 = dpp_shr1_f(a1, 0.f);
                    int En = dpp_shr1_i(E, E);
                    int Ep = max(E, En);
                    float t1 = LDEXPF(n1, En - Ep);
                    float o0 = LDEXPF(a0, E - Ep), o1 = LDEXPF(a1, E - Ep);
                    E = Ep;
                    a0 = (o0 + t1) * p0;
                    a1 = __builtin_fmaf(skip1f, t1, o1 + o0) * p1;
                }
                if (t == t_idx) {
                    int l0 = lane * 2;
                    if (l0 == l1) { capA = a0; capEA = E; }
                    if (l0 == l2) { capB = a0; capEB = E; }
                    if (l0 + 1 == l1) { capA = a1; capEA = E; }
                    if (l0 + 1 == l2) { capB = a1; capEB = E; }
                }
                if ((t & 3) == 3) {
                    float m = fmaxf(a0, a1);
                    int k = ((__float_as_int(m) >> 23) & 255) - 127;
                    a0 = LDEXPF(a0, -k); a1 = LDEXPF(a1, -k); E += k;
                }
            }
            finish_loss(capA, capB, capEA, capEB, lane, loss_err, b);
        }

    } else if (blk < 64) {
        // ---------------- err backward ----------------
        const int b = blk - 32;
        const int* tgt = err_tgt + b * 50;
        const int L = 101; int tl = err_tl[b];
        int l1 = min(2 * tl, L - 1), l2 = max(min(2 * tl - 1, L - 1), 0);
        float skip1f;
        {
            int l = lane * 2 + 1; bool sk = false;
            if (l >= 3 && l <= 100) { int i = l >> 1; sk = (tgt[i] != tgt[i - 1]); }
            skip1f = sk ? 1.f : 0.f;
        }
        float skp2 = dpp_shl1_f(skip1f, 0.f);
        const char* base = (const char*)(Perr + (size_t)b * T * 128);
        const char* srcl = base + (size_t)(T - 1) * 256 + lane * 4;
        auto rd = [&](int row) -> unsigned {
            return *((const unsigned*)(ringc + (size_t)(row & 31) * 256) + lane);
        };
        float g0 = 0.f, g1 = 0.f; int E = 0; float f = 1.f;
        auto bstep = [&](unsigned cur) {
            float p0 = __uint_as_float(cur << 16);
            float p1 = __uint_as_float(cur & 0xFFFF0000u);
            float t0 = dpp_shl1_f(g0, 0.f) * f;
            float t1 = dpp_shl1_f(g1, 0.f) * f;
            float ng0 = (g0 + g1) * p0;
            g1 = __builtin_fmaf(skp2, t1, g1 + t0) * p1;
            g0 = ng0;
        };
        auto rex = [&]() {
            float m = fmaxf(g0, g1);
            int k = ((__float_as_int(m) >> 23) & 255) - 127;
            g0 = LDEXPF(g0, -k); g1 = LDEXPF(g1, -k); E += k;
            int En = dpp_shl1_i(E, E);
            int Ep = max(E, En);
            int eo = E - Ep;
            g0 = LDEXPF(g0, eo); g1 = LDEXPF(g1, eo);
            E = Ep;
            int d = max(En - Ep, -127);
            f = __int_as_float((d + 127) << 23);
        };
#pragma unroll
        for (int r = 0; r < 24; ++r)
            async4(ringc + (size_t)(r & 31) * 256, srcl - (size_t)r * 256);
        {   // chunk 0: init at t=T-1
#pragma unroll
            for (int r = 24; r < 32; ++r)
                async4(ringc + (size_t)(r & 31) * 256, srcl - (size_t)r * 256);
            asm volatile("s_waitcnt vmcnt(16)" ::: "memory");
            __builtin_amdgcn_sched_barrier(0);
            unsigned q[8];
#pragma unroll
            for (int j = 0; j < 8; ++j) q[j] = rd(j);
            float p0 = __uint_as_float(q[0] << 16);
            float p1 = __uint_as_float(q[0] & 0xFFFF0000u);
            int l0 = lane * 2;
            g0 = (l0 == l1 || l0 == l2) ? p0 : 0.f;
            g1 = (l0 + 1 == l1 || l0 + 1 == l2) ? p1 : 0.f;
            E = 0; f = 1.f;
#pragma unroll
            for (int j = 1; j < 8; ++j) {
                bstep(q[j]);
                if (j == 3 || j == 7) rex();
            }
        }
        for (int k = 1; k < NCH; ++k) {
            if (k + 3 < NCH) {
                int bs = (k + 3) * 8;
#pragma unroll
                for (int r = 0; r < 8; ++r)
                    async4(ringc + (size_t)((bs + r) & 31) * 256,
                           srcl - (size_t)(bs + r) * 256);
                asm volatile("s_waitcnt vmcnt(16)" ::: "memory");
            } else {
                asm volatile("s_waitcnt vmcnt(0)" ::: "memory");
            }
            __builtin_amdgcn_sched_barrier(0);
            unsigned q[8];
#pragma unroll
            for (int j = 0; j < 8; ++j) q[j] = rd(k * 8 + j);
#pragma unroll
            for (int j = 0; j < 8; ++j) {
                bstep(q[j]);
                if (j == 3 || j == 7) rex();
            }
        }
        gerr[b * 128 + lane * 2] = g0;
        gerr[b * 128 + lane * 2 + 1] = g1;
        gerrE[b * 64 + lane] = E;

    } else if (blk < 96) {
        // ---------------- ph forward ----------------
        const int b = blk - 64;
        int t_idx = min(max(ph_il[b] - 1, 0), T - 1);
        const int* tgt = ph_tgt + b * 200;
        float skf[8];
#pragma unroll
        for (int s = 0; s < 8; ++s) {
            int l = lane * 8 + s; float v = 0.f;
            if ((s & 1) && l >= 3 && l <= 400) {
                int i = l >> 1; v = (tgt[i] != tgt[i - 1]) ? 1.f : 0.f;
            }
            skf[s] = v;
        }
        const char* base = (const char*)(Pph + (size_t)b * T * 512);
        float a[8];
#pragma unroll
        for (int s = 0; s < 8; ++s) a[s] = 0.f;
        int E = 0; float f = 1.f;
        auto rd4 = [&](int row) -> uint4 {
            return *((const uint4*)(ringc + (size_t)(row & 31) * 1024) + lane);
        };
        auto fstep = [&](const uint4& q) {
            float p[8]; unpack8(q, p);
            float n7 = dpp_shr1_f(a[7], 0.f) * f;
            float n6 = dpp_shr1_f(a[6], 0.f) * f;
            float an[8];
#pragma unroll
            for (int s = 0; s < 8; ++s) {
                float am1 = (s == 0) ? n7 : a[s - 1];
                float am2 = (s == 0) ? n6 : ((s == 1) ? n7 : a[s - 2]);
                an[s] = __builtin_fmaf(skf[s], am2, a[s] + am1) * p[s];
            }
#pragma unroll
            for (int s = 0; s < 8; ++s) a[s] = an[s];
        };
        auto rex = [&]() {
            float m = a[0];
#pragma unroll
            for (int s = 1; s < 8; ++s) m = fmaxf(m, a[s]);
            int k = ((__float_as_int(m) >> 23) & 255) - 127;
#pragma unroll
            for (int s = 0; s < 8; ++s) a[s] = LDEXPF(a[s], -k);
            E += k;
            int En = dpp_shr1_i(E, E);
            int Ep = max(E, En);
            int eo = E - Ep;
#pragma unroll
            for (int s = 0; s < 8; ++s) a[s] = LDEXPF(a[s], eo);
            E = Ep;
            int d = max(En - Ep, -127);
            f = __int_as_float((d + 127) << 23);
        };

        if (t_idx == T - 1) {
            const char* srcl = base + lane * 16;
#pragma unroll
            for (int r = 0; r < 24; ++r)
                async16(ringc + (size_t)(r & 31) * 1024, srcl + (size_t)r * 1024);
            {
#pragma unroll
                for (int r = 24; r < 32; ++r)
                    async16(ringc + (size_t)(r & 31) * 1024, srcl + (size_t)r * 1024);
                asm volatile("s_waitcnt vmcnt(16)" ::: "memory");
                __builtin_amdgcn_sched_barrier(0);
                uint4 q[8];
#pragma unroll
                for (int j = 0; j < 8; ++j) q[j] = rd4(j);
                float p[8]; unpack8(q[0], p);
#pragma unroll
                for (int s = 0; s < 8; ++s) {
                    int l = lane * 8 + s;
                    a[s] = (l < 2) ? p[s] : 0.f;
                }
                E = 0; f = 1.f;
#pragma unroll
                for (int j = 1; j < 8; ++j) {
                    fstep(q[j]);
                    if (j == 3 || j == 7) rex();
                }
            }
            for (int k = 1; k < NCH; ++k) {
                if (k + 3 < NCH) {
                    int bs = (k + 3) * 8;
#pragma unroll
                    for (int r = 0; r < 8; ++r)
                        async16(ringc + (size_t)((bs + r) & 31) * 1024,
                                srcl + (size_t)(bs + r) * 1024);
                    asm volatile("s_waitcnt vmcnt(16)" ::: "memory");
                } else {
                    asm volatile("s_waitcnt vmcnt(0)" ::: "memory");
                }
                __builtin_amdgcn_sched_barrier(0);
                uint4 q[8];
#pragma unroll
                for (int j = 0; j < 8; ++j) q[j] = rd4(k * 8 + j);
#pragma unroll
                for (int j = 0; j < 8; ++j) {
                    fstep(q[j]);
                    if (j == 3 || j == 7) rex();
                }
            }
#pragma unroll
            for (int s = 0; s < 8; ++s) aph[b * 512 + lane * 8 + s] = a[s];
            aphE[b * 64 + lane] = E;
        } else {
            // fallback: full forward with capture + per-step alignment (rare)
            const int L = 401; int tl = ph_tl[b];
            int l1 = min(2 * tl, L - 1), l2 = max(min(2 * tl - 1, L - 1), 0);
            float capA = 0.f, capB = 0.f; int capEA = 0, capEB = 0;
            for (int t = 0; t < T; ++t) {
                uint4 q = *((const uint4*)(base + (size_t)t * 1024) + lane);
                float p[8]; unpack8(q, p);
                if (t == 0) {
#pragma unroll
                    for (int s = 0; s < 8; ++s) {
                        int l = lane * 8 + s;
                        a[s] = (l < 2) ? p[s] : 0.f;
                    }
                    E = 0;
                } else {
                    float n7 = dpp_shr1_f(a[7], 0.f), n6 = dpp_shr1_f(a[6], 0.f);
                    int En = dpp_shr1_i(E, E);
                    int Ep = max(E, En);
                    float o[8];
#pragma unroll
                    for (int s = 0; s < 8; ++s) o[s] = LDEXPF(a[s], E - Ep);
                    float s7 = LDEXPF(n7, En - Ep), s6 = LDEXPF(n6, En - Ep);
                    E = Ep;
#pragma unroll
                    for (int s = 0; s < 8; ++s) {
                        float am1 = (s == 0) ? s7 : o[s - 1];
                        float am2 = (s == 0) ? s6 : ((s == 1) ? s7 : o[s - 2]);
                        a[s] = __builtin_fmaf(skf[s], am2, o[s] + am1) * p[s];
                    }
                }
                if (t == t_idx) {
#pragma unroll
                    for (int s = 0; s < 8; ++s) {
                        int l = lane * 8 + s;
                        if (l == l1) { capA = a[s]; capEA = E; }
                        if (l == l2) { capB = a[s]; capEB = E; }
                    }
                }
                if ((t & 3) == 3) {
                    float m = a[0];
#pragma unroll
                    for (int s = 1; s < 8; ++s) m = fmaxf(m, a[s]);
                    int k = ((__float_as_int(m) >> 23) & 255) - 127;
#pragma unroll
                    for (int s = 0; s < 8; ++s) a[s] = LDEXPF(a[s], -k);
                    E += k;
                }
            }
            finish_loss(capA, capB, capEA, capEB, lane, loss_ph, b);
        }

    } else {
        // ---------------- ph backward ----------------
        const int b = blk - 96;
        const int* tgt = ph_tgt + b * 200;
        const int L = 401; int tl = ph_tl[b];
        int l1 = min(2 * tl, L - 1), l2 = max(min(2 * tl - 1, L - 1), 0);
        float skf[8];
#pragma unroll
        for (int s = 0; s < 8; ++s) {
            int l = lane * 8 + s; float v = 0.f;
            if ((s & 1) && l >= 3 && l <= 400) {
                int i = l >> 1; v = (tgt[i] != tgt[i - 1]) ? 1.f : 0.f;
            }
            skf[s] = v;
        }
        float nskf1 = dpp_shl1_f(skf[1], 0.f);
        float skp2[8];
        skp2[0] = 0.f; skp2[1] = skf[3]; skp2[2] = 0.f; skp2[3] = skf[5];
        skp2[4] = 0.f; skp2[5] = skf[7]; skp2[6] = 0.f; skp2[7] = nskf1;

        const char* base = (const char*)(Pph + (size_t)b * T * 512);
        const char* srcl = base + (size_t)(T - 1) * 1024 + lane * 16;
        auto rd4 = [&](int row) -> uint4 {
            return *((const uint4*)(ringc + (size_t)(row & 31) * 1024) + lane);
        };
        float g[8];
#pragma unroll
        for (int s = 0; s < 8; ++s) g[s] = 0.f;
        int E = 0; float f = 1.f;
        auto bstep = [&](const uint4& q) {
            float p[8]; unpack8(q, p);
            float nb0 = dpp_shl1_f(g[0], 0.f) * f;
            float nb1 = dpp_shl1_f(g[1], 0.f) * f;
            float gn[8];
#pragma unroll
            for (int s = 0; s < 8; ++s) {
                float bp1 = (s < 7) ? g[s + 1] : nb0;
                float bp2 = (s < 6) ? g[s + 2] : ((s == 6) ? nb0 : nb1);
                gn[s] = __builtin_fmaf(skp2[s], bp2, g[s] + bp1) * p[s];
            }
#pragma unroll
            for (int s = 0; s < 8; ++s) g[s] = gn[s];
        };
        auto rex = [&]() {
            float m = g[0];
#pragma unroll
            for (int s = 1; s < 8; ++s) m = fmaxf(m, g[s]);
            int k = ((__float_as_int(m) >> 23) & 255) - 127;
#pragma unroll
            for (int s = 0; s < 8; ++s) g[s] = LDEXPF(g[s], -k);
            E += k;
            int En = dpp_shl1_i(E, E);
            int Ep = max(E, En);
            int eo = E - Ep;
#pragma unroll
            for (int s = 0; s < 8; ++s) g[s] = LDEXPF(g[s], eo);
            E = Ep;
            int d = max(En - Ep, -127);
            f = __int_as_float((d + 127) << 23);
        };
#pragma unroll
        for (int r = 0; r < 24; ++r)
            async16(ringc + (size_t)(r & 31) * 1024, srcl - (size_t)r * 1024);
        {
#pragma unroll
            for (int r = 24; r < 32; ++r)
                async16(ringc + (size_t)(r & 31) * 1024, srcl - (size_t)r * 1024);
            asm volatile("s_waitcnt vmcnt(16)" ::: "memory");
            __builtin_amdgcn_sched_barrier(0);
            uint4 q[8];
#pragma unroll
            for (int j = 0; j < 8; ++j) q[j] = rd4(j);
            float p[8]; unpack8(q[0], p);
#pragma unroll
            for (int s = 0; s < 8; ++s) {
                int l = lane * 8 + s;
                g[s] = (l == l1 || l == l2) ? p[s] : 0.f;
            }
            E = 0; f = 1.f;
#pragma unroll
            for (int j = 1; j < 8; ++j) {
                bstep(q[j]);
                if (j == 3 || j == 7) rex();
            }
        }
        for (int k = 1; k < NCH; ++k) {
            if (k + 3 < NCH) {
                int bs = (k + 3) * 8;
#pragma unroll
                for (int r = 0; r < 8; ++r)
                    async16(ringc + (size_t)((bs + r) & 31) * 1024,
                            srcl - (size_t)(bs + r) * 1024);
                asm volatile("s_waitcnt vmcnt(16)" ::: "memory");
            } else {
                asm volatile("s_waitcnt vmcnt(0)" ::: "memory");
            }
            __builtin_amdgcn_sched_barrier(0);
            uint4 q[8];
#pragma unroll
            for (int j = 0; j < 8; ++j) q[j] = rd4(k * 8 + j);
#pragma unroll
            for (int j = 0; j < 8; ++j) {
                bstep(q[j]);
                if (j == 3 || j == 7) rex();
            }
        }
#pragma unroll
        for (int s = 0; s < 8; ++s) gph[b * 512 + lane * 8 + s] = g[s];
        gphE[b * 64 + lane] = E;
    }
}

// ===========================================================================
// combine: p = sum_l alpha_tm[l] * (g[l] + g[l+1] + allow[l+2]*g[l+2])
// ===========================================================================
__global__ __launch_bounds__(64) void combine_kernel(
    const int* __restrict__ err_tgt, const int* __restrict__ ph_tgt,
    const int* __restrict__ err_il, const int* __restrict__ ph_il,
    const float* __restrict__ aerr, const int* __restrict__ aerrE,
    const float* __restrict__ gerr, const int* __restrict__ gerrE,
    const float* __restrict__ aph, const int* __restrict__ aphE,
    const float* __restrict__ gph, const int* __restrict__ gphE,
    float* __restrict__ loss_err, float* __restrict__ loss_ph, int T) {
    const int blk = blockIdx.x;
    const int lane = threadIdx.x & 63;
    if (blk < 32) {
        const int b = blk;
        int t_idx = min(max(err_il[b] - 1, 0), T - 1);
        if (t_idx != T - 1) return;
        const int* tgt = err_tgt + b * 50;
        float skip1f;
        {
            int l = lane * 2 + 1; bool sk = false;
            if (l >= 3 && l <= 100) { int i = l >> 1; sk = (tgt[i] != tgt[i - 1]); }
            skip1f = sk ? 1.f : 0.f;
        }
        float a0 = aerr[b * 128 + lane * 2], a1 = aerr[b * 128 + lane * 2 + 1];
        int Ea = aerrE[b * 64 + lane];
        float g0 = gerr[b * 128 + lane * 2], g1 = gerr[b * 128 + lane * 2 + 1];
        int Eb = gerrE[b * 64 + lane];
        float nb0 = __shfl_down(g0, 1), nb1 = __shfl_down(g1, 1);
        int Ebn = __shfl_down(Eb, 1);
        float skp2 = __shfl_down(skip1f, 1);
        if (lane == 63) { nb0 = 0.f; nb1 = 0.f; Ebn = Eb; skp2 = 0.f; }
        int Em = max(Eb, Ebn);
        float o0 = LDEXPF(g0, Eb - Em), o1 = LDEXPF(g1, Eb - Em);
        float t0 = LDEXPF(nb0, Ebn - Em), t1 = LDEXPF(nb1, Ebn - Em);
        float bc0 = o0 + o1;
        float bc1 = __builtin_fmaf(skp2, t1, o1 + t0);
        float dot = __builtin_fmaf(a0, bc0, a1 * bc1);
        float v = (dot > 0.f) ? (float)(Ea + Em) + LOG2F(dot) : NEG2;
        float mm = v;
#pragma unroll
        for (int i = 1; i < 64; i <<= 1) mm = fmaxf(mm, __shfl_xor(mm, i));
        float sum = EXP2F(v - mm);
#pragma unroll
        for (int i = 1; i < 64; i <<= 1) sum += __shfl_xor(sum, i);
        if (lane == 0) loss_err[b] = -(mm + LOG2F(sum)) * LN2;
    } else {
        const int b = blk - 32;
        int t_idx = min(max(ph_il[b] - 1, 0), T - 1);
        if (t_idx != T - 1) return;
        const int* tgt = ph_tgt + b * 200;
        float skf[8];
#pragma unroll
        for (int s = 0; s < 8; ++s) {
            int l = lane * 8 + s; float v = 0.f;
            if ((s & 1) && l >= 3 && l <= 400) {
                int i = l >> 1; v = (tgt[i] != tgt[i - 1]) ? 1.f : 0.f;
            }
            skf[s] = v;
        }
        float a[8], g[8];
#pragma unroll
        for (int s = 0; s < 8; ++s) {
            a[s] = aph[b * 512 + lane * 8 + s];
            g[s] = gph[b * 512 + lane * 8 + s];
        }
        int Ea = aphE[b * 64 + lane];
        int Eb = gphE[b * 64 + lane];
        float nb0 = __shfl_down(g[0], 1), nb1 = __shfl_down(g[1], 1);
        int Ebn = __shfl_down(Eb, 1);
        float nskf1 = __shfl_down(skf[1], 1);
        if (lane == 63) { nb0 = 0.f; nb1 = 0.f; Ebn = Eb; nskf1 = 0.f; }
        float skp2[8];
        skp2[0] = 0.f; skp2[1] = skf[3]; skp2[2] = 0.f; skp2[3] = skf[5];
        skp2[4] = 0.f; skp2[5] = skf[7]; skp2[6] = 0.f; skp2[7] = nskf1;
        int Em = max(Eb, Ebn);
        float o[8];
#pragma unroll
        for (int s = 0; s < 8; ++s) o[s] = LDEXPF(g[s], Eb - Em);
        float t0 = LDEXPF(nb0, Ebn - Em), t1 = LDEXPF(nb1, Ebn - Em);
        float dot = 0.f;
#pragma unroll
        for (int s = 0; s < 8; ++s) {
            float bp1 = (s < 7) ? o[s + 1] : t0;
            float bp2 = (s < 6) ? o[s + 2] : ((s == 6) ? t0 : t1);
            float bc = __builtin_fmaf(skp2[s], bp2, o[s] + bp1);
            dot = __builtin_fmaf(a[s], bc, dot);
        }
        float v = (dot > 0.f) ? (float)(Ea + Em) + LOG2F(dot) : NEG2;
        float mm = v;
#pragma unroll
        for (int i = 1; i < 64; i <<= 1) mm = fmaxf(mm, __shfl_xor(mm, i));
        float sum = EXP2F(v - mm);
#pragma unroll
        for (int i = 1; i < 64; i <<= 1) sum += __shfl_xor(sum, i);
        if (lane == 0) loss_ph[b] = -(mm + LOG2F(sum)) * LN2;
    }
}

// ===========================================================================
// FALLBACK PATH (round-5, proven) — used only if ws_size too small
// ===========================================================================
__global__ void denom_err_kernel(const float* __restrict__ logits,
                                 float* __restrict__ d2, int rows) {
    int r = blockIdx.x * blockDim.x + threadIdx.x;
    if (r >= rows) return;
    const float* row = logits + (size_t)r * 8;
    float x[8];
#pragma unroll
    for (int i = 0; i < 8; ++i) x[i] = row[i] * LOG2E;
    float m = x[0];
#pragma unroll
    for (int i = 1; i < 8; ++i) m = fmaxf(m, x[i]);
    float s = 0.f;
#pragma unroll
    for (int i = 0; i < 8; ++i) s += EXP2F(x[i] - m);
    d2[r] = m + LOG2F(s);
}

__global__ void denom_ph_kernel(const float* __restrict__ logits,
                                float* __restrict__ d2, int rows) {
    int wave = (int)((blockIdx.x * (size_t)blockDim.x + threadIdx.x) >> 6);
    int lane = threadIdx.x & 63;
    if (wave >= rows) return;
    const float* row = logits + (size_t)wave * 128;
    float x0 = row[lane] * LOG2E;
    float x1 = row[lane + 64] * LOG2E;
    float m = fmaxf(x0, x1);
#pragma unroll
    for (int i = 1; i < 64; i <<= 1) m = fmaxf(m, __shfl_xor(m, i));
    float s = EXP2F(x0 - m) + EXP2F(x1 - m);
#pragma unroll
    for (int i = 1; i < 64; i <<= 1) s += __shfl_xor(s, i);
    if (lane == 0) d2[wave] = m + LOG2F(s);
}

template <int NST, int C>
__device__ __forceinline__ void gather_row(const float* ringL, const float* ringD,
                                           int row, const int (&clsoff)[NST],
                                           float (&g)[NST], float& gd) {
    int base = (row & 63) * C;
#pragma unroll
    for (int s = 0; s < NST; ++s) g[s] = ringL[base + clsoff[s]];
    gd = ringD[row & 63];
}

template <int C, int CHV>
__device__ __forceinline__ void stage_load(const float* __restrict__ lrow,
                                           const float* __restrict__ d2row,
                                           int t0, int T, int lane,
                                           float4 (&st)[CHV], float4& stD) {
#pragma unroll
    for (int j = 0; j < CHV; ++j) {
        int e = t0 * C + (j * 64 + lane) * 4;
        e = min(e, T * C - 4);
        st[j] = *(const float4*)(lrow + e);
    }
    if (lane < 8) {
        int e = t0 + lane * 4;
        e = min(e, T - 4);
        stD = *(const float4*)(d2row + e);
    }
}

template <int C, int CHV>
__device__ __forceinline__ void stage_write(float* ringL, float* ringD, int t0, int lane,
                                            const float4 (&st)[CHV], const float4& stD) {
    int base = (t0 & 63) * C;
#pragma unroll
    for (int j = 0; j < CHV; ++j)
        *(float4*)(ringL + base + (j * 64 + lane) * 4) = st[j];
    if (lane < 8)
        *(float4*)(ringD + (t0 & 63) + lane * 4) = stD;
}

template <int NST>
__device__ __forceinline__ void do_step_lin(
    float (&a)[NST], int& E,
    const float (&g)[NST], float gd,
    const float (&validf)[NST], const bool (&skipb)[NST],
    int lane, int t, int t_idx, int l1, int l2,
    float& capA, float& capB, int& capEA, int& capEB) {
    float p[NST];
#pragma unroll
    for (int s = 0; s < NST; ++s)
        p[s] = validf[s] * EXP2F(__builtin_fmaf(g[s], LOG2E, -gd));
    if (t == 0) {
#pragma unroll
        for (int s = 0; s < NST; ++s) {
            int l = lane * NST + s;
            a[s] = (l < 2) ? p[s] : 0.f;
        }
        E = 0;
    } else {
        float top1 = dpp_shr1_f(a[NST - 1], 0.f);
        int   En   = dpp_shr1_i(E, E);
        int Ep = max(E, En);
        float t1 = LDEXPF(top1, En - Ep);
        float ao[NST];
#pragma unroll
        for (int s = 0; s < NST; ++s) ao[s] = LDEXPF(a[s], E - Ep);
        E = Ep;
#pragma unroll
        for (int s = 0; s < NST; ++s) {
            float sum;
            if (s == 0)            sum = ao[0] + t1;
            else if (s == 1)       sum = ao[1] + ao[0] + (skipb[1] ? t1 : 0.f);
            else if ((s & 1) == 0) sum = ao[s] + ao[s - 1];
            else                   sum = ao[s] + ao[s - 1] + (skipb[s] ? ao[s - 2] : 0.f);
            a[s] = sum * p[s];
        }
    }
    if (t == t_idx) {
#pragma unroll
        for (int s = 0; s < NST; ++s) {
            int l = lane * NST + s;
            if (l == l1) { capA = a[s]; capEA = E; }
            if (l == l2) { capB = a[s]; capEB = E; }
        }
    }
    if ((t & 1) == 1) {
        float m = a[0];
#pragma unroll
        for (int s = 1; s < NST; ++s) m = fmaxf(m, a[s]);
        int k = ((__float_as_int(m) >> 23) & 255) - 127;
#pragma unroll
        for (int s = 0; s < NST; ++s) a[s] = LDEXPF(a[s], -k);
        E += k;
    }
}

template <int NST, int C, int S, int CHV>
__device__ __forceinline__ void ctc_run(
    const float* __restrict__ lrow, const float* __restrict__ d2row,
    const int* __restrict__ tgt, int T, int t_idx, int l1, int l2,
    float* ringL, float* ringD, float* __restrict__ loss_out, int b) {
    const int lane = threadIdx.x & 63;
    const int L = 2 * S + 1;
    int clsoff[NST];
    bool skipb[NST];
    float validf[NST];
#pragma unroll
    for (int s = 0; s < NST; ++s) {
        int l = lane * NST + s;
        bool v = (l < L);
        int li = v ? l : 0;
        int c = 0;
        bool sk = false;
        if (li & 1) {
            int i = li >> 1;
            c = tgt[i];
            if (li >= 3) sk = (c != tgt[i - 1]);
        }
        clsoff[s] = c;
        skipb[s] = sk;
        validf[s] = v ? 1.f : 0.f;
    }
    float4 st[CHV];
    float4 stD = make_float4(0.f, 0.f, 0.f, 0.f);
    stage_load<C, CHV>(lrow, d2row, 0, T, lane, st, stD);
    stage_write<C, CHV>(ringL, ringD, 0, lane, st, stD);
    stage_load<C, CHV>(lrow, d2row, 32, T, lane, st, stD);
    stage_write<C, CHV>(ringL, ringD, 32, lane, st, stD);
    stage_load<C, CHV>(lrow, d2row, 64, T, lane, st, stD);
    float gA[NST], gB[NST], dA, dB;
    gather_row<NST, C>(ringL, ringD, 0, clsoff, gA, dA);
    gather_row<NST, C>(ringL, ringD, 1, clsoff, gB, dB);
    float a[NST];
#pragma unroll
    for (int s = 0; s < NST; ++s) a[s] = 0.f;
    int E = 0;
    float capA = 0.f, capB = 0.f;
    int capEA = 0, capEB = 0;
    const int NCH = (T + 31) >> 5;
    for (int c = 0; c < NCH; ++c) {
        int t0 = c << 5;
        int half = min(32, T - t0) >> 1;
        for (int j = 0; j < half; ++j) {
            int t = t0 + 2 * j;
            do_step_lin<NST>(a, E, gA, dA, validf, skipb, lane, t, t_idx, l1, l2,
                             capA, capB, capEA, capEB);
            gather_row<NST, C>(ringL, ringD, t + 2, clsoff, gA, dA);
            do_step_lin<NST>(a, E, gB, dB, validf, skipb, lane, t + 1, t_idx, l1, l2,
                             capA, capB, capEA, capEB);
            gather_row<NST, C>(ringL, ringD, t + 3, clsoff, gB, dB);
            if (j == 14 && c + 2 < NCH) {
                stage_write<C, CHV>(ringL, ringD, t0 + 64, lane, st, stD);
                if (c + 3 < NCH)
                    stage_load<C, CHV>(lrow, d2row, t0 + 96, T, lane, st, stD);
            }
        }
    }
    float vA = (capA > 0.f) ? (float)capEA + LOG2F(capA) : NEG2;
    float vB = (capB > 0.f) ? (float)capEB + LOG2F(capB) : NEG2;
    float mm = fmaxf(vA, vB);
#pragma unroll
    for (int i = 1; i < 64; i <<= 1) mm = fmaxf(mm, __shfl_xor(mm, i));
    float sum = EXP2F(vA - mm) + EXP2F(vB - mm);
#pragma unroll
    for (int i = 1; i < 64; i <<= 1) sum += __shfl_xor(sum, i);
    if (lane == 0) loss_out[b] = -(mm + LOG2F(sum)) * LN2;
}

__global__ __launch_bounds__(64) void ctc_kernel(
    const float* __restrict__ err_logits, const float* __restrict__ ph_logits,
    const int* __restrict__ err_tgt, const int* __restrict__ ph_tgt,
    const int* __restrict__ err_il, const int* __restrict__ ph_il,
    const int* __restrict__ err_tl, const int* __restrict__ ph_tl,
    const float* __restrict__ d2_err, const float* __restrict__ d2_ph,
    float* __restrict__ loss_err, float* __restrict__ loss_ph, int T) {
    __shared__ float ringL[64 * 128];
    __shared__ float ringD[64];
    int blk = blockIdx.x;
    if (blk < 32) {
        int b = blk;
        const int L = 101;
        int tl = err_tl[b];
        int l1 = min(2 * tl, L - 1);
        int l2 = max(min(2 * tl - 1, L - 1), 0);
        int t_idx = min(max(err_il[b] - 1, 0), T - 1);
        ctc_run<2, 8, 50, 1>(err_logits + (size_t)b * T * 8, d2_err + (size_t)b * T,
                             err_tgt + b * 50, T, t_idx, l1, l2, ringL, ringD,
                             loss_err, b);
    } else {
        int b = blk - 32;
        const int L = 401;
        int tl = ph_tl[b];
        int l1 = min(2 * tl, L - 1);
        int l2 = max(min(2 * tl - 1, L - 1), 0);
        int t_idx = min(max(ph_il[b] - 1, 0), T - 1);
        ctc_run<8, 128, 200, 16>(ph_logits + (size_t)b * T * 128, d2_ph + (size_t)b * T,
                                 ph_tgt + b * 200, T, t_idx, l1, l2, ringL, ringD,
                                 loss_ph, b);
    }
}

// ---------------------------------------------------------------------------
// Final: focal transform + means + total. One wave.
// ---------------------------------------------------------------------------
__global__ void final_kernel(const float* __restrict__ loss_err,
                             const float* __restrict__ loss_ph,
                             float* __restrict__ out) {
    int lane = threadIdx.x & 63;
    float fe = 0.f, fp = 0.f;
    if (lane < 32) {
        float l = fmaxf(loss_err[lane], 1e-6f);
        float pt = fminf(fmaxf(EXP2F(-l * LOG2E), 1e-6f), 1.0f);
        float om = 1.f - pt;
        fe = om * om * l;
        l = fmaxf(loss_ph[lane], 1e-6f);
        pt = fminf(fmaxf(EXP2F(-l * LOG2E), 1e-6f), 1.0f);
        om = 1.f - pt;
        fp = om * om * l;
    }
#pragma unroll
    for (int i = 1; i < 64; i <<= 1) {
        fe += __shfl_xor(fe, i);
        fp += __shfl_xor(fp, i);
    }
    if (lane == 0) {
        float err = fe / 32.f;
        float ph = fp / 32.f;
        out[0] = err + ph;
        out[1] = err;
        out[2] = ph;
    }
}

// ---------------------------------------------------------------------------
extern "C" void kernel_launch(void* const* d_in, const int* in_sizes, int n_in,
                              void* d_out, int out_size, void* d_ws, size_t ws_size,
                              hipStream_t stream) {
    const int B = 32, T = 2000;
    const float* err_logits = (const float*)d_in[0];  // [32,2000,8]
    const float* ph_logits  = (const float*)d_in[1];  // [32,2000,128]
    const int* err_tgt = (const int*)d_in[2];         // [32,50]
    const int* ph_tgt  = (const int*)d_in[3];         // [32,200]
    const int* err_il  = (const int*)d_in[4];
    const int* ph_il   = (const int*)d_in[5];
    const int* err_tl  = (const int*)d_in[6];
    const int* ph_tl   = (const int*)d_in[7];
    float* out = (float*)d_out;

    const size_t PH_US  = (size_t)B * T * 512;   // ushorts
    const size_t ERR_US = (size_t)B * T * 128;   // ushorts

    char* p = (char*)d_ws;
    unsigned short* Pph  = (unsigned short*)p; p += PH_US * 2;
    unsigned short* Perr = (unsigned short*)p; p += ERR_US * 2;
    float* aph  = (float*)p; p += (size_t)B * 512 * 4;
    int*   aphE = (int*)p;   p += (size_t)B * 64 * 4;
    float* gph  = (float*)p; p += (size_t)B * 512 * 4;
    int*   gphE = (int*)p;   p += (size_t)B * 64 * 4;
    float* aerr = (float*)p; p += (size_t)B * 128 * 4;
    int*   aerrE= (int*)p;   p += (size_t)B * 64 * 4;
    float* gerr = (float*)p; p += (size_t)B * 128 * 4;
    int*   gerrE= (int*)p;   p += (size_t)B * 64 * 4;
    float* loss_err = (float*)p; p += B * 4;
    float* loss_ph  = (float*)p; p += B * 4;
    const size_t need = (size_t)(p - (char*)d_ws);

    if (ws_size >= need) {
        // -------- fast path: probs -> fwd/bwd ctc -> combine -> final --------
        prob_kernel<<<32000, 256, 0, stream>>>(ph_logits, ph_tgt, Pph,
                                               err_logits, err_tgt, Perr);
        ctc7_kernel<<<128, 64, 0, stream>>>(Perr, Pph, err_tgt, ph_tgt,
                                            err_il, ph_il, err_tl, ph_tl,
                                            aerr, aerrE, gerr, gerrE,
                                            aph, aphE, gph, gphE,
                                            loss_err, loss_ph, T);
        combine_kernel<<<64, 64, 0, stream>>>(err_tgt, ph_tgt, err_il, ph_il,
                                              aerr, aerrE, gerr, gerrE,
                                              aph, aphE, gph, gphE,
                                              loss_err, loss_ph, T);
        final_kernel<<<1, 64, 0, stream>>>(loss_err, loss_ph, out);
    } else {
        // -------- fallback (round-5) --------
        float* ws = (float*)d_ws;
        float* d2_err   = ws;
        float* d2_ph    = ws + 64000;
        float* le = ws + 128000;
        float* lp = ws + 128032;
        int rows = B * T;
        denom_err_kernel<<<(rows + 255) / 256, 256, 0, stream>>>(err_logits, d2_err, rows);
        denom_ph_kernel<<<rows / 4, 256, 0, stream>>>(ph_logits, d2_ph, rows);
        ctc_kernel<<<64, 64, 0, stream>>>(err_logits, ph_logits, err_tgt, ph_tgt,
                                          err_il, ph_il, err_tl, ph_tl,
                                          d2_err, d2_ph, le, lp, T);
        final_kernel<<<1, 64, 0, stream>>>(le, lp, out);
    }
}